// Round 7
// baseline (571.989 us; speedup 1.0000x reference)
//
#include <hip/hip_runtime.h>
#include <hip/hip_bf16.h>
#include <math.h>

#define NEG_SLOPE 0.2f

typedef __attribute__((ext_vector_type(8))) short bf16x8;
typedef __attribute__((ext_vector_type(4))) float f32x4;

__device__ __forceinline__ float sigmoidf(float x){ return 1.f/(1.f+expf(-x)); }

// pack v into (hi,lo) bf16 pair: hi=bf16(v), lo=bf16(v-hi); hi|lo<<16.
__device__ __forceinline__ unsigned pack_split(float v){
  __hip_bfloat16 hi = __float2bfloat16(v);
  float rem = v - __bfloat162float(hi);
  __hip_bfloat16 lo = __float2bfloat16(rem);
  unsigned short uh = __builtin_bit_cast(unsigned short, hi);
  unsigned short ul = __builtin_bit_cast(unsigned short, lo);
  return (unsigned)uh | ((unsigned)ul << 16);
}

// ============================ init + CSR build ==============================
__global__ void init_kernel(int* counts, int* gstart, int* gend,
                            float* rsum, float* lsum,
                            int* pad1, int* pad2, int npadints,
                            int n, int b){
  int i = blockIdx.x*blockDim.x + threadIdx.x;
  if (i < n) counts[i] = 0;
  if (i < b){ gstart[i] = 0; gend[i] = 0; }
  if (i < 3*b*128) rsum[i] = 0.f;
  if (i < 3*b) lsum[i] = 0.f;
  if (i < npadints){ pad1[i] = 0; pad2[i] = 0; }   // zero bf16-split pad rows
}

__global__ void build_kernel(const int* __restrict__ ei, const int* __restrict__ batch,
                             int* counts, int* gstart, int* gend, int E, int n){
  int i = blockIdx.x*blockDim.x + threadIdx.x;
  if (i < E) atomicAdd(&counts[ei[E+i]], 1);
  if (i < n){
    int b = batch[i];
    if (i == 0 || batch[i-1] != b) gstart[b] = i;
    if (i == n-1 || batch[i+1] != b) gend[b] = i+1;
  }
}

__global__ void scan_kernel(const int* __restrict__ counts, int* offs, int* cursor, int n){
  const int T = 1024;
  int tid = threadIdx.x;
  int chunk = (n + T - 1)/T;
  int base = tid*chunk;
  int local = 0;
  for (int i=0;i<chunk;i++){ int idx=base+i; if (idx<n) local += counts[idx]; }
  __shared__ int ss[T];
  ss[tid]=local; __syncthreads();
  for (int off=1; off<T; off<<=1){
    int v = (tid>=off)? ss[tid-off] : 0;
    __syncthreads();
    ss[tid]+=v;
    __syncthreads();
  }
  int run = ss[tid]-local;
  for (int i=0;i<chunk;i++){
    int idx=base+i;
    if (idx<n){ offs[idx]=run; cursor[idx]=run; run += counts[idx]; }
  }
  if (tid==T-1) offs[n]=run;
}

__global__ void fill_kernel(const int* __restrict__ ei, int* cursor, int* csr, int E){
  int i = blockIdx.x*blockDim.x + threadIdx.x;
  if (i<E){
    int dst = ei[E+i];
    int pos = atomicAdd(&cursor[dst],1);
    csr[pos] = ei[i];
  }
}

// ===================== split-bf16 conversions ===============================
// x [Nrows,128] fp32 -> xs [Mpad,256] bf16 (hi,lo interleaved); pad rows zero.
__global__ void convert_x(const float* __restrict__ x, unsigned* __restrict__ xs,
                          int Nrows, int Mpad){
  int idx = blockIdx.x*blockDim.x + threadIdx.x;
  if (idx >= Mpad*128) return;
  int r = idx >> 7;
  float v = (r < Nrows) ? x[idx] : 0.f;
  xs[idx] = pack_split(v);
}

// W [K,N] fp32 -> WT [N,2K] bf16 split, transposed (so GEMM B-frags read
// contiguous k-runs from LDS).
__global__ void convert_wT(const float* __restrict__ W, unsigned* __restrict__ WT,
                           int K, int N){
  int idx = blockIdx.x*blockDim.x + threadIdx.x;
  if (idx >= K*N) return;
  int k = idx / N, n = idx - k*N;
  WT[(size_t)n*K + k] = pack_split(W[idx]);
}

// ===================== bf16 MFMA GEMM (exact via split-K doubling) ==========
// C[M,N] = A[Mpad,Ktot] x BT[N,Ktot]^T, bf16 inputs, fp32 out. 128x128 tile,
// 4 waves x (4x4) mfma_f32_16x16x32_bf16 frags. Row pad +8 shorts -> LDS frag
// reads are 2-way bank-aliased (free, m136).
__global__ __launch_bounds__(256) void gemm_bf16(
    const short* __restrict__ A, const short* __restrict__ BT,
    float* __restrict__ C, int M, int Ktot, int N){
  __shared__ short As[128][72];
  __shared__ short Bs[128][72];
  int tid = threadIdx.x;
  int wave = tid>>6, lane = tid&63;
  int quad = lane>>4, l16 = lane&15;
  int wm = wave>>1, wn = wave&1;
  int bm = blockIdx.x*128, bn = blockIdx.y*128;
  f32x4 acc[4][4];
  #pragma unroll
  for (int i=0;i<4;i++)
    #pragma unroll
    for (int j=0;j<4;j++)
      acc[i][j] = (f32x4){0.f,0.f,0.f,0.f};
  int rs = tid>>3;          // 0..31
  int seg = (tid&7)*8;      // shorts
  for (int k0=0; k0<Ktot; k0+=64){
    int4 ra[4], rb[4];
    #pragma unroll
    for (int p=0;p<4;p++){
      int r = p*32 + rs;
      ra[p] = *(const int4*)(A + (size_t)(bm+r)*Ktot + k0 + seg);
      rb[p] = *(const int4*)(BT + (size_t)(bn+r)*Ktot + k0 + seg);
    }
    __syncthreads();
    #pragma unroll
    for (int p=0;p<4;p++){
      int r = p*32 + rs;
      *(int4*)&As[r][seg] = ra[p];
      *(int4*)&Bs[r][seg] = rb[p];
    }
    __syncthreads();
    #pragma unroll
    for (int kk=0;kk<2;kk++){
      bf16x8 af[4], bf[4];
      #pragma unroll
      for (int f=0;f<4;f++){
        af[f] = *(bf16x8*)&As[wm*64 + f*16 + l16][kk*32 + quad*8];
        bf[f] = *(bf16x8*)&Bs[wn*64 + f*16 + l16][kk*32 + quad*8];
      }
      #pragma unroll
      for (int mf=0;mf<4;mf++)
        #pragma unroll
        for (int nf=0;nf<4;nf++)
          acc[mf][nf] = __builtin_amdgcn_mfma_f32_16x16x32_bf16(af[mf], bf[nf], acc[mf][nf], 0,0,0);
    }
  }
  // C/D layout: col=lane&15, row=quad*4+reg (m89/m91 verified)
  int col0 = bn + wn*64 + l16;
  #pragma unroll
  for (int mf=0;mf<4;mf++){
    int row0 = bm + wm*64 + mf*16 + quad*4;
    #pragma unroll
    for (int r=0;r<4;r++){
      int row = row0 + r;
      if (row < M){
        #pragma unroll
        for (int nf=0;nf<4;nf++)
          C[(size_t)row*N + col0 + nf*16] = acc[mf][nf][r];
      }
    }
  }
}

// ============== per-node attention logits s,d = <h, a_src/a_dst> ============
template<int H, int C>
__global__ void sd_kernel(const float* __restrict__ h, const float* __restrict__ asrc,
                          const float* __restrict__ adst, float* __restrict__ s,
                          float* __restrict__ d, int n_nodes){
  int wave = threadIdx.x >> 6, lane = threadIdx.x & 63;
  int n = blockIdx.x*4 + wave;
  if (n >= n_nodes) return;
  const float* hn = h + (size_t)n*H*C;
  #pragma unroll
  for (int hd=0; hd<H; ++hd){
    float ps=0.f, pd=0.f;
    for (int c=lane; c<C; c+=64){
      float v = hn[hd*C+c];
      ps += v*asrc[hd*C+c];
      pd += v*adst[hd*C+c];
    }
    #pragma unroll
    for (int off=32; off; off>>=1){ ps += __shfl_down(ps,off); pd += __shfl_down(pd,off); }
    if (lane==0){ s[n*H+hd]=ps; d[n*H+hd]=pd; }
  }
}

// ================= GAT aggregation: softmax over in-edges ====================
// SPLIT=true: write packed bf16 (hi,lo) rows for the next layer's MFMA GEMM
// (same bytes as fp32 - free). SPLIT=false: write fp32 (feeds set2set).
template<int H, int C, bool SPLIT>
__global__ __launch_bounds__(256) void agg_kernel(
    const float* __restrict__ hbuf, const float* __restrict__ s,
    const float* __restrict__ d, const int* __restrict__ offs,
    const int* __restrict__ csr, const float* __restrict__ bias,
    float* __restrict__ yf, unsigned* __restrict__ ys, int n_nodes){
  constexpr int HC = H*C;
  constexpr int VEC = HC/64;            // 4 (H=4,C=64) or 2 (H=1,C=128)
  int n = blockIdx.x;
  int tid = threadIdx.x;
  int wave = tid>>6, lane = tid&63;
  __shared__ float sdst[H];
  __shared__ float sl[H];
  __shared__ float sw[64*H];
  __shared__ int ssrc[64];
  __shared__ float facc[4][HC];
  if (tid < H) sdst[tid] = d[n*H+tid];
  int start = offs[n];
  int cnt = offs[n+1]-start;
  int cnt1 = cnt+1;                      // + self loop
  __syncthreads();
  float acc[VEC] = {};
  float lp[H];
  #pragma unroll
  for (int h=0;h<H;h++) lp[h]=0.f;
  for (int base=0; base<cnt1; base+=64){
    int nchunk = min(64, cnt1-base);
    if (tid < nchunk){
      int i = base+tid;
      int src = (i==cnt) ? n : csr[start+i];
      ssrc[tid]=src;
      if (H == 4){
        float4 sv = *reinterpret_cast<const float4*>(s + (size_t)src*4);
        float ev[4] = {sv.x, sv.y, sv.z, sv.w};
        #pragma unroll
        for (int h=0;h<4;h++){
          float e = ev[h] + sdst[h];
          e = e>=0.f ? e : NEG_SLOPE*e;
          float w = expf(e);
          sw[tid*4+h]=w;
          lp[h]+=w;
        }
      } else {
        float e = s[src] + sdst[0];
        e = e>=0.f ? e : NEG_SLOPE*e;
        float w = expf(e);
        sw[tid]=w;
        lp[0]+=w;
      }
    }
    __syncthreads();
    for (int j=wave; j<nchunk; j+=4){
      int src = ssrc[j];
      const float* hp = hbuf + (size_t)src*HC + lane*VEC;
      if (VEC == 4){
        float wt = sw[j*H + (lane>>4)];
        float4 hv = *reinterpret_cast<const float4*>(hp);
        acc[0]+=wt*hv.x; acc[1]+=wt*hv.y; acc[2]+=wt*hv.z; acc[3]+=wt*hv.w;
      } else {
        float wt = sw[j];
        float2 hv = *reinterpret_cast<const float2*>(hp);
        acc[0]+=wt*hv.x; acc[1]+=wt*hv.y;
      }
    }
    __syncthreads();
  }
  if (wave==0){
    #pragma unroll
    for (int off=32; off; off>>=1)
      #pragma unroll
      for (int h=0;h<H;h++) lp[h] += __shfl_down(lp[h],off);
    if (lane==0)
      #pragma unroll
      for (int h=0;h<H;h++) sl[h]=lp[h];
  }
  #pragma unroll
  for (int v=0;v<VEC;v++) facc[wave][lane*VEC+v] = acc[v];
  __syncthreads();
  if (tid < HC){
    float a = facc[0][tid]+facc[1][tid]+facc[2][tid]+facc[3][tid];
    int head = tid / C;
    float o = a/(sl[head]+1e-16f) + bias[tid];
    o = o>0.f ? o : expm1f(o);
    if (SPLIT){
      ys[(size_t)n*HC + tid] = pack_split(o);
    } else {
      yf[(size_t)n*HC + tid] = o;
    }
  }
}

// ======================= Set2Set, grid-parallel =============================
__global__ __launch_bounds__(256) void read_kernel(
    const float* __restrict__ x, const float* __restrict__ q,
    const int* __restrict__ batch,
    float* __restrict__ rsum, float* __restrict__ lsum, int N){
  int tid = threadIdx.x;
  int wave = tid>>6, lane = tid&63;
  int c0 = blockIdx.x*32;
  if (c0 >= N) return;
  __shared__ float ws[32];
  __shared__ int gb[32];
  if (tid < 32 && c0+tid < N) gb[tid] = batch[c0+tid];
  __syncthreads();
  #pragma unroll
  for (int j=0;j<8;j++){
    int k = wave*8 + j;
    int i = c0 + k;
    if (i < N){
      int g = gb[k];
      float2 xv = *reinterpret_cast<const float2*>(x + (size_t)i*128 + lane*2);
      float2 qv = *reinterpret_cast<const float2*>(q + (size_t)g*128 + lane*2);
      float p = xv.x*qv.x + xv.y*qv.y;
      #pragma unroll
      for (int off=32; off; off>>=1) p += __shfl_down(p, off);
      if (lane==0) ws[k] = expf(p);
    }
  }
  __syncthreads();
  if (tid < 128){
    int col = tid;
    int endi = min(c0+32, N);
    int curg = gb[0];
    float acc = 0.f, lacc = 0.f;
    for (int i=c0; i<endi; ++i){
      int g = gb[i-c0];
      if (g != curg){
        atomicAdd(&rsum[curg*128+col], acc);
        if (col==0) atomicAdd(&lsum[curg], lacc);
        acc = 0.f; lacc = 0.f; curg = g;
      }
      float w = ws[i-c0];
      acc += w * x[(size_t)i*128+col];
      lacc += w;
    }
    atomicAdd(&rsum[curg*128+col], acc);
    if (col==0) atomicAdd(&lsum[curg], lacc);
  }
}

template<int STEP>
__global__ __launch_bounds__(256) void s2s_step_kernel(
    const float* __restrict__ rsum, const float* __restrict__ lsum,
    float* __restrict__ hc, float* __restrict__ qbuf,
    const float* __restrict__ Wih, const float* __restrict__ Whh,
    const float* __restrict__ bih, const float* __restrict__ bhh,
    const float* __restrict__ gfeat,
    const float* __restrict__ gW1, const float* __restrict__ gb1,
    const float* __restrict__ gW2, const float* __restrict__ gb2,
    const float* __restrict__ mW1, const float* __restrict__ mb1,
    const float* __restrict__ mW2, const float* __restrict__ mb2,
    float* __restrict__ out, int B){
  int b = blockIdx.x, tid = threadIdx.x;
  __shared__ float qs[256];

  if (STEP > 0){
    if (tid < 128){
      const float* rs = rsum + (size_t)(STEP-1)*B*128 + (size_t)b*128;
      float ls = lsum[(STEP-1)*B + b];
      qs[tid]     = qbuf[b*128+tid];
      qs[128+tid] = rs[tid] / (ls + 1e-16f);
    }
    __syncthreads();
  }

  if (STEP < 3){
    __shared__ float hs[128], gsh[512];
    if (STEP > 0){ if (tid<128) hs[tid] = hc[(size_t)b*128+tid]; }
    __syncthreads();
    #pragma unroll
    for (int p=0;p<2;p++){
      int j = tid + p*256;
      float a = bih[j] + bhh[j];
      if (STEP > 0){
        const float* wi = Wih + (size_t)j*256;
        for (int k=0;k<256;k+=4)
          a += qs[k]*wi[k] + qs[k+1]*wi[k+1] + qs[k+2]*wi[k+2] + qs[k+3]*wi[k+3];
        const float* wh = Whh + (size_t)j*128;
        for (int k=0;k<128;k+=4)
          a += hs[k]*wh[k] + hs[k+1]*wh[k+1] + hs[k+2]*wh[k+2] + hs[k+3]*wh[k+3];
      }
      gsh[j] = a;
    }
    __syncthreads();
    if (tid < 128){
      float cprev = (STEP==0) ? 0.f : hc[(size_t)(B+b)*128+tid];
      float ig = sigmoidf(gsh[tid]);
      float fg = sigmoidf(gsh[128+tid]);
      float gg = tanhf(gsh[256+tid]);
      float og = sigmoidf(gsh[384+tid]);
      float c2 = fg*cprev + ig*gg;
      float h2 = og*tanhf(c2);
      hc[(size_t)b*128+tid] = h2;
      hc[(size_t)(B+b)*128+tid] = c2;
      qbuf[b*128+tid] = h2;
    }
  } else {
    __shared__ float z[288], gf1[64], hid[128];
    z[tid] = qs[tid];
    if (tid < 64){
      float a = gb1[tid];
      for (int k=0;k<9;k++) a += gfeat[b*9+k]*gW1[k*64+tid];
      gf1[tid] = a>0.f ? a : 0.f;
    }
    __syncthreads();
    if (tid < 32){
      float a = gb2[tid];
      for (int k=0;k<64;k++) a += gf1[k]*gW2[k*32+tid];
      z[256+tid] = a;
    }
    __syncthreads();
    if (tid < 128){
      float a = mb1[tid];
      for (int k=0;k<288;k++) a += z[k]*mW1[(size_t)k*128+tid];
      hid[tid] = a>0.f ? a : 0.f;
    }
    __syncthreads();
    if (tid < 4){
      float a = mb2[tid];
      for (int k=0;k<128;k++) a += hid[k]*mW2[k*4+tid];
      out[b*4+tid] = a;
    }
  }
}

// ================================ launch ====================================
extern "C" void kernel_launch(void* const* d_in, const int* in_sizes, int n_in,
                              void* d_out, int out_size, void* d_ws, size_t ws_size,
                              hipStream_t stream) {
  const float* x     = (const float*)d_in[0];
  const int*   ei    = (const int*)d_in[1];
  const int*   batch = (const int*)d_in[2];
  const float* gfeat = (const float*)d_in[3];
  const float* W1    = (const float*)d_in[4];
  const float* as1   = (const float*)d_in[5];
  const float* ad1   = (const float*)d_in[6];
  const float* b1    = (const float*)d_in[7];
  const float* W2    = (const float*)d_in[8];
  const float* as2   = (const float*)d_in[9];
  const float* ad2   = (const float*)d_in[10];
  const float* b2    = (const float*)d_in[11];
  const float* W3    = (const float*)d_in[12];
  const float* as3   = (const float*)d_in[13];
  const float* ad3   = (const float*)d_in[14];
  const float* b3    = (const float*)d_in[15];
  const float* Wih   = (const float*)d_in[16];
  const float* Whh   = (const float*)d_in[17];
  const float* bih   = (const float*)d_in[18];
  const float* bhh   = (const float*)d_in[19];
  const float* gW1   = (const float*)d_in[20];
  const float* gb1   = (const float*)d_in[21];
  const float* gW2   = (const float*)d_in[22];
  const float* gb2   = (const float*)d_in[23];
  const float* mW1   = (const float*)d_in[24];
  const float* mb1   = (const float*)d_in[25];
  const float* mW2   = (const float*)d_in[26];
  const float* mb2   = (const float*)d_in[27];

  const int N = in_sizes[0]/128;   // 20000
  const int E = in_sizes[1]/2;     // 320000
  const int B = in_sizes[3]/9;     // 64
  const int Mpad = ((N + 127)/128)*128;   // 20096

  char* ws = (char*)d_ws;
  size_t off = 0;
  auto alloc = [&](size_t bytes)->char*{
    char* p = ws + off;
    off += (bytes + 255) & ~(size_t)255;
    return p;
  };
  float*    hbuf    = (float*)alloc((size_t)N*256*4);
  unsigned* xsplit  = (unsigned*)alloc((size_t)Mpad*128*4);   // [Mpad,256] bf16
  unsigned* ysplit1 = (unsigned*)alloc((size_t)Mpad*256*4);   // [Mpad,512] bf16
  unsigned* ysplit2 = (unsigned*)alloc((size_t)Mpad*256*4);   // [Mpad,512] bf16
  float*    ybuf    = (float*)alloc((size_t)N*128*4);         // layer-3 out
  unsigned* WT1     = (unsigned*)alloc((size_t)128*256*4);    // [256,256] bf16
  unsigned* WT2     = (unsigned*)alloc((size_t)256*256*4);    // [256,512] bf16
  unsigned* WT3     = (unsigned*)alloc((size_t)256*128*4);    // [128,512] bf16
  float* sbuf   = (float*)alloc((size_t)N*4*4);
  float* dbuf   = (float*)alloc((size_t)N*4*4);
  int*   counts = (int*)alloc((size_t)N*4);
  int*   offs   = (int*)alloc((size_t)(N+1)*4);
  int*   cursor = (int*)alloc((size_t)N*4);
  int*   csr    = (int*)alloc((size_t)E*4);
  int*   gstart = (int*)alloc((size_t)B*4);
  int*   gend   = (int*)alloc((size_t)B*4);
  float* hcbuf  = (float*)alloc((size_t)2*B*128*4);
  float* qbuf   = (float*)alloc((size_t)B*128*4);
  float* rsum   = (float*)alloc((size_t)3*B*128*4);
  float* lsum   = (float*)alloc((size_t)3*B*4);

  int npadints = (Mpad - N)*256;   // pad rows of ysplit1/2, in uints
  int nInit = max(max(N, 3*B*128), npadints);
  init_kernel<<<(nInit+255)/256, 256, 0, stream>>>(counts, gstart, gend,
      rsum, lsum, (int*)(ysplit1 + (size_t)N*256), (int*)(ysplit2 + (size_t)N*256),
      npadints, N, B);
  int gridEN = (max(E,N)+255)/256;
  build_kernel<<<gridEN, 256, 0, stream>>>(ei, batch, counts, gstart, gend, E, N);
  scan_kernel<<<1, 1024, 0, stream>>>(counts, offs, cursor, N);
  fill_kernel<<<(E+255)/256, 256, 0, stream>>>(ei, cursor, csr, E);

  // conversions
  convert_x<<<(Mpad*128+255)/256, 256, 0, stream>>>(x, xsplit, N, Mpad);
  convert_wT<<<(128*256+255)/256, 256, 0, stream>>>(W1, WT1, 128, 256);
  convert_wT<<<(256*256+255)/256, 256, 0, stream>>>(W2, WT2, 256, 256);
  convert_wT<<<(256*128+255)/256, 256, 0, stream>>>(W3, WT3, 256, 128);

  int gm = Mpad/128;
  // ---- layer 1: x -> h[N,256] -> ysplit1
  gemm_bf16<<<dim3(gm,2), 256, 0, stream>>>((const short*)xsplit, (const short*)WT1, hbuf, N, 256, 256);
  sd_kernel<4,64><<<(N+3)/4, 256, 0, stream>>>(hbuf, as1, ad1, sbuf, dbuf, N);
  agg_kernel<4,64,true><<<N, 256, 0, stream>>>(hbuf, sbuf, dbuf, offs, csr, b1, nullptr, ysplit1, N);
  // ---- layer 2: ysplit1 -> h[N,256] -> ysplit2
  gemm_bf16<<<dim3(gm,2), 256, 0, stream>>>((const short*)ysplit1, (const short*)WT2, hbuf, N, 512, 256);
  sd_kernel<4,64><<<(N+3)/4, 256, 0, stream>>>(hbuf, as2, ad2, sbuf, dbuf, N);
  agg_kernel<4,64,true><<<N, 256, 0, stream>>>(hbuf, sbuf, dbuf, offs, csr, b2, nullptr, ysplit2, N);
  // ---- layer 3: ysplit2 -> h[N,128] -> ybuf (fp32, feeds set2set)
  gemm_bf16<<<dim3(gm,1), 256, 0, stream>>>((const short*)ysplit2, (const short*)WT3, hbuf, N, 512, 128);
  sd_kernel<1,128><<<(N+3)/4, 256, 0, stream>>>(hbuf, as3, ad3, sbuf, dbuf, N);
  agg_kernel<1,128,false><<<N, 256, 0, stream>>>(hbuf, sbuf, dbuf, offs, csr, b3, ybuf, nullptr, N);

  // ---- set2set (fused grid-parallel readout) + scorer ----
  int gr = (N+31)/32;
  s2s_step_kernel<0><<<B, 256, 0, stream>>>(rsum, lsum, hcbuf, qbuf,
      Wih, Whh, bih, bhh, gfeat, gW1, gb1, gW2, gb2, mW1, mb1, mW2, mb2, (float*)d_out, B);
  read_kernel<<<gr, 256, 0, stream>>>(ybuf, qbuf, batch, rsum + 0*(size_t)B*128, lsum + 0*B, N);
  s2s_step_kernel<1><<<B, 256, 0, stream>>>(rsum, lsum, hcbuf, qbuf,
      Wih, Whh, bih, bhh, gfeat, gW1, gb1, gW2, gb2, mW1, mb1, mW2, mb2, (float*)d_out, B);
  read_kernel<<<gr, 256, 0, stream>>>(ybuf, qbuf, batch, rsum + 1*(size_t)B*128, lsum + 1*B, N);
  s2s_step_kernel<2><<<B, 256, 0, stream>>>(rsum, lsum, hcbuf, qbuf,
      Wih, Whh, bih, bhh, gfeat, gW1, gb1, gW2, gb2, mW1, mb1, mW2, mb2, (float*)d_out, B);
  read_kernel<<<gr, 256, 0, stream>>>(ybuf, qbuf, batch, rsum + 2*(size_t)B*128, lsum + 2*B, N);
  s2s_step_kernel<3><<<B, 256, 0, stream>>>(rsum, lsum, hcbuf, qbuf,
      Wih, Whh, bih, bhh, gfeat, gW1, gb1, gW2, gb2, mW1, mb1, mW2, mb2, (float*)d_out, B);
}

// Round 8
// 567.080 us; speedup vs baseline: 1.0087x; 1.0087x over previous
//
#include <hip/hip_runtime.h>
#include <hip/hip_bf16.h>
#include <math.h>

#define NEG_SLOPE 0.2f

typedef __attribute__((ext_vector_type(8))) short bf16x8;
typedef __attribute__((ext_vector_type(4))) float f32x4;

__device__ __forceinline__ float sigmoidf(float x){ return 1.f/(1.f+expf(-x)); }

// pack v into (hi,lo) bf16 pair: hi=bf16(v), lo=bf16(v-hi); hi|lo<<16.
__device__ __forceinline__ unsigned pack_split(float v){
  __hip_bfloat16 hi = __float2bfloat16(v);
  float rem = v - __bfloat162float(hi);
  __hip_bfloat16 lo = __float2bfloat16(rem);
  unsigned short uh = __builtin_bit_cast(unsigned short, hi);
  unsigned short ul = __builtin_bit_cast(unsigned short, lo);
  return (unsigned)uh | ((unsigned)ul << 16);
}

// ============================ init + CSR build ==============================
__global__ void init_kernel(int* counts, int* gstart, int* gend,
                            float* rsum, float* lsum,
                            int* pad1, int* pad2, int npadints,
                            int n, int b){
  int i = blockIdx.x*blockDim.x + threadIdx.x;
  if (i < n) counts[i] = 0;
  if (i < b){ gstart[i] = 0; gend[i] = 0; }
  if (i < 3*b*128) rsum[i] = 0.f;
  if (i < 3*b) lsum[i] = 0.f;
  if (i < npadints){ pad1[i] = 0; pad2[i] = 0; }
}

__global__ void build_kernel(const int* __restrict__ ei, const int* __restrict__ batch,
                             int* counts, int* gstart, int* gend, int E, int n){
  int i = blockIdx.x*blockDim.x + threadIdx.x;
  if (i < E) atomicAdd(&counts[ei[E+i]], 1);
  if (i < n){
    int b = batch[i];
    if (i == 0 || batch[i-1] != b) gstart[b] = i;
    if (i == n-1 || batch[i+1] != b) gend[b] = i+1;
  }
}

__global__ void scan_kernel(const int* __restrict__ counts, int* offs, int* cursor, int n){
  const int T = 1024;
  int tid = threadIdx.x;
  int chunk = (n + T - 1)/T;
  int base = tid*chunk;
  int local = 0;
  for (int i=0;i<chunk;i++){ int idx=base+i; if (idx<n) local += counts[idx]; }
  __shared__ int ss[T];
  ss[tid]=local; __syncthreads();
  for (int off=1; off<T; off<<=1){
    int v = (tid>=off)? ss[tid-off] : 0;
    __syncthreads();
    ss[tid]+=v;
    __syncthreads();
  }
  int run = ss[tid]-local;
  for (int i=0;i<chunk;i++){
    int idx=base+i;
    if (idx<n){ offs[idx]=run; cursor[idx]=run; run += counts[idx]; }
  }
  if (tid==T-1) offs[n]=run;
}

__global__ void fill_kernel(const int* __restrict__ ei, int* cursor, int* csr, int E){
  int i = blockIdx.x*blockDim.x + threadIdx.x;
  if (i<E){
    int dst = ei[E+i];
    int pos = atomicAdd(&cursor[dst],1);
    csr[pos] = ei[i];
  }
}

// ===================== split-bf16 conversions (single launch) ===============
__global__ void convert_all(const float* __restrict__ x, unsigned* __restrict__ xs,
                            int Nrows, int Mpad,
                            const float* __restrict__ W1, unsigned* __restrict__ WT1,
                            const float* __restrict__ W2, unsigned* __restrict__ WT2,
                            const float* __restrict__ W3, unsigned* __restrict__ WT3){
  int idx = blockIdx.x*blockDim.x + threadIdx.x;
  int n0 = Mpad*128;
  if (idx < n0){
    int r = idx >> 7;
    xs[idx] = pack_split(r < Nrows ? x[idx] : 0.f);
    return;
  }
  idx -= n0;
  if (idx < 128*256){           // W1 [128,256] -> WT1 [256 rows][K=128 uints]
    int k = idx>>8, n = idx&255;
    WT1[(size_t)n*128 + k] = pack_split(W1[idx]);
    return;
  }
  idx -= 128*256;
  if (idx < 256*256){           // W2 [256,256] -> WT2 [256][256]
    int k = idx>>8, n = idx&255;
    WT2[(size_t)n*256 + k] = pack_split(W2[idx]);
    return;
  }
  idx -= 256*256;
  if (idx < 256*128){           // W3 [256,128] -> WT3 [128][256]
    int k = idx>>7, n = idx&127;
    WT3[(size_t)n*256 + k] = pack_split(W3[idx]);
  }
}

// ===================== bf16 MFMA GEMM (exact via split-K doubling) ==========
// C[M,N] = A[Mpad,Ktot] x BT[N,Ktot]^T. 64x128 tile (rows x cols), 256 thr,
// 4 waves: wave w owns rows w*16..w*16+15, 8 col-frags. Grid ~628 blocks
// (~2.5/CU) so barrier drains overlap across co-resident blocks (round-7's
// 128x128 tile gave only 1.2 blocks/CU -> latency-bound).
__global__ __launch_bounds__(256) void gemm_bf16(
    const short* __restrict__ A, const short* __restrict__ BT,
    float* __restrict__ C, int M, int Ktot, int N){
  __shared__ short As[64][72];
  __shared__ short Bs[128][72];
  int tid = threadIdx.x;
  int wave = tid>>6, lane = tid&63;
  int quad = lane>>4, l16 = lane&15;
  int bm = blockIdx.x*64, bn = blockIdx.y*128;
  f32x4 acc[8];
  #pragma unroll
  for (int i=0;i<8;i++) acc[i] = (f32x4){0.f,0.f,0.f,0.f};
  int rr = tid>>3;          // 0..31
  int seg = (tid&7)*8;      // shorts
  for (int k0=0; k0<Ktot; k0+=64){
    int4 ra[2], rb[4];
    #pragma unroll
    for (int p=0;p<2;p++)
      ra[p] = *(const int4*)(A + (size_t)(bm + p*32 + rr)*Ktot + k0 + seg);
    #pragma unroll
    for (int p=0;p<4;p++)
      rb[p] = *(const int4*)(BT + (size_t)(bn + p*32 + rr)*Ktot + k0 + seg);
    __syncthreads();
    #pragma unroll
    for (int p=0;p<2;p++) *(int4*)&As[p*32+rr][seg] = ra[p];
    #pragma unroll
    for (int p=0;p<4;p++) *(int4*)&Bs[p*32+rr][seg] = rb[p];
    __syncthreads();
    #pragma unroll
    for (int kk=0;kk<2;kk++){
      bf16x8 af = *(bf16x8*)&As[wave*16 + l16][kk*32 + quad*8];
      #pragma unroll
      for (int nf=0;nf<8;nf++){
        bf16x8 bf = *(bf16x8*)&Bs[nf*16 + l16][kk*32 + quad*8];
        acc[nf] = __builtin_amdgcn_mfma_f32_16x16x32_bf16(af, bf, acc[nf], 0,0,0);
      }
    }
  }
  // C/D layout: col=lane&15 (from B-frag), row=quad*4+reg (m89/m91 verified)
  #pragma unroll
  for (int r=0;r<4;r++){
    int row = bm + wave*16 + quad*4 + r;
    if (row < M){
      #pragma unroll
      for (int nf=0;nf<8;nf++)
        C[(size_t)row*N + bn + nf*16 + l16] = acc[nf][r];
    }
  }
}

// ============== per-node attention logits s,d = <h, a_src/a_dst> ============
// One wave per node; lane loads one float4 of the row (perfectly coalesced),
// per-head shfl_xor reduction.
template<int H, int C>
__global__ void sd_kernel(const float* __restrict__ h, const float* __restrict__ asrc,
                          const float* __restrict__ adst, float* __restrict__ s,
                          float* __restrict__ d, int n_nodes){
  constexpr int HC = H*C;            // 256 (H=4) or 128 (H=1)
  int wave = threadIdx.x >> 6, lane = threadIdx.x & 63;
  int n = blockIdx.x*4 + wave;
  if (n >= n_nodes) return;
  if (HC == 256){
    float4 hv = *reinterpret_cast<const float4*>(h + (size_t)n*256 + lane*4);
    float4 av = *reinterpret_cast<const float4*>(asrc + lane*4);
    float4 dv = *reinterpret_cast<const float4*>(adst + lane*4);
    float ps = hv.x*av.x + hv.y*av.y + hv.z*av.z + hv.w*av.w;
    float pd = hv.x*dv.x + hv.y*dv.y + hv.z*dv.z + hv.w*dv.w;
    #pragma unroll
    for (int off=1; off<16; off<<=1){ ps += __shfl_xor(ps,off); pd += __shfl_xor(pd,off); }
    if ((lane&15)==0){
      int head = lane>>4;
      s[n*4+head]=ps; d[n*4+head]=pd;
    }
  } else {
    if (lane < 32){
      float4 hv = *reinterpret_cast<const float4*>(h + (size_t)n*128 + lane*4);
      float4 av = *reinterpret_cast<const float4*>(asrc + lane*4);
      float4 dv = *reinterpret_cast<const float4*>(adst + lane*4);
      float ps = hv.x*av.x + hv.y*av.y + hv.z*av.z + hv.w*av.w;
      float pd = hv.x*dv.x + hv.y*dv.y + hv.z*dv.z + hv.w*dv.w;
      #pragma unroll
      for (int off=1; off<32; off<<=1){ ps += __shfl_xor(ps,off); pd += __shfl_xor(pd,off); }
      if (lane==0){ s[n]=ps; d[n]=pd; }
    }
  }
}

// ================= GAT aggregation: softmax over in-edges ====================
template<int H, int C, bool SPLIT>
__global__ __launch_bounds__(256) void agg_kernel(
    const float* __restrict__ hbuf, const float* __restrict__ s,
    const float* __restrict__ d, const int* __restrict__ offs,
    const int* __restrict__ csr, const float* __restrict__ bias,
    float* __restrict__ yf, unsigned* __restrict__ ys, int n_nodes){
  constexpr int HC = H*C;
  constexpr int VEC = HC/64;            // 4 (H=4,C=64) or 2 (H=1,C=128)
  int n = blockIdx.x;
  int tid = threadIdx.x;
  int wave = tid>>6, lane = tid&63;
  __shared__ float sdst[H];
  __shared__ float sl[H];
  __shared__ float sw[64*H];
  __shared__ int ssrc[64];
  __shared__ float facc[4][HC];
  if (tid < H) sdst[tid] = d[n*H+tid];
  int start = offs[n];
  int cnt = offs[n+1]-start;
  int cnt1 = cnt+1;                      // + self loop
  __syncthreads();
  float acc[VEC] = {};
  float lp[H];
  #pragma unroll
  for (int h=0;h<H;h++) lp[h]=0.f;
  for (int base=0; base<cnt1; base+=64){
    int nchunk = min(64, cnt1-base);
    if (tid < nchunk){
      int i = base+tid;
      int src = (i==cnt) ? n : csr[start+i];
      ssrc[tid]=src;
      if (H == 4){
        float4 sv = *reinterpret_cast<const float4*>(s + (size_t)src*4);
        float ev[4] = {sv.x, sv.y, sv.z, sv.w};
        #pragma unroll
        for (int h=0;h<4;h++){
          float e = ev[h] + sdst[h];
          e = e>=0.f ? e : NEG_SLOPE*e;
          float w = expf(e);
          sw[tid*4+h]=w;
          lp[h]+=w;
        }
      } else {
        float e = s[src] + sdst[0];
        e = e>=0.f ? e : NEG_SLOPE*e;
        float w = expf(e);
        sw[tid]=w;
        lp[0]+=w;
      }
    }
    __syncthreads();
    for (int j=wave; j<nchunk; j+=4){
      int src = ssrc[j];
      const float* hp = hbuf + (size_t)src*HC + lane*VEC;
      if (VEC == 4){
        float wt = sw[j*H + (lane>>4)];
        float4 hv = *reinterpret_cast<const float4*>(hp);
        acc[0]+=wt*hv.x; acc[1]+=wt*hv.y; acc[2]+=wt*hv.z; acc[3]+=wt*hv.w;
      } else {
        float wt = sw[j];
        float2 hv = *reinterpret_cast<const float2*>(hp);
        acc[0]+=wt*hv.x; acc[1]+=wt*hv.y;
      }
    }
    __syncthreads();
  }
  if (wave==0){
    #pragma unroll
    for (int off=32; off; off>>=1)
      #pragma unroll
      for (int h=0;h<H;h++) lp[h] += __shfl_down(lp[h],off);
    if (lane==0)
      #pragma unroll
      for (int h=0;h<H;h++) sl[h]=lp[h];
  }
  #pragma unroll
  for (int v=0;v<VEC;v++) facc[wave][lane*VEC+v] = acc[v];
  __syncthreads();
  if (tid < HC){
    float a = facc[0][tid]+facc[1][tid]+facc[2][tid]+facc[3][tid];
    int head = tid / C;
    float o = a/(sl[head]+1e-16f) + bias[tid];
    o = o>0.f ? o : expm1f(o);
    if (SPLIT){
      ys[(size_t)n*HC + tid] = pack_split(o);
    } else {
      yf[(size_t)n*HC + tid] = o;
    }
  }
}

// ======================= Set2Set, grid-parallel =============================
__global__ __launch_bounds__(256) void read_kernel(
    const float* __restrict__ x, const float* __restrict__ q,
    const int* __restrict__ batch,
    float* __restrict__ rsum, float* __restrict__ lsum, int N){
  int tid = threadIdx.x;
  int wave = tid>>6, lane = tid&63;
  int c0 = blockIdx.x*32;
  if (c0 >= N) return;
  __shared__ float ws[32];
  __shared__ int gb[32];
  if (tid < 32 && c0+tid < N) gb[tid] = batch[c0+tid];
  __syncthreads();
  #pragma unroll
  for (int j=0;j<8;j++){
    int k = wave*8 + j;
    int i = c0 + k;
    if (i < N){
      int g = gb[k];
      float2 xv = *reinterpret_cast<const float2*>(x + (size_t)i*128 + lane*2);
      float2 qv = *reinterpret_cast<const float2*>(q + (size_t)g*128 + lane*2);
      float p = xv.x*qv.x + xv.y*qv.y;
      #pragma unroll
      for (int off=32; off; off>>=1) p += __shfl_down(p, off);
      if (lane==0) ws[k] = expf(p);
    }
  }
  __syncthreads();
  if (tid < 128){
    int col = tid;
    int endi = min(c0+32, N);
    int curg = gb[0];
    float acc = 0.f, lacc = 0.f;
    for (int i=c0; i<endi; ++i){
      int g = gb[i-c0];
      if (g != curg){
        atomicAdd(&rsum[curg*128+col], acc);
        if (col==0) atomicAdd(&lsum[curg], lacc);
        acc = 0.f; lacc = 0.f; curg = g;
      }
      float w = ws[i-c0];
      acc += w * x[(size_t)i*128+col];
      lacc += w;
    }
    atomicAdd(&rsum[curg*128+col], acc);
    if (col==0) atomicAdd(&lsum[curg], lacc);
  }
}

template<int STEP>
__global__ __launch_bounds__(256) void s2s_step_kernel(
    const float* __restrict__ rsum, const float* __restrict__ lsum,
    float* __restrict__ hc, float* __restrict__ qbuf,
    const float* __restrict__ Wih, const float* __restrict__ Whh,
    const float* __restrict__ bih, const float* __restrict__ bhh,
    const float* __restrict__ gfeat,
    const float* __restrict__ gW1, const float* __restrict__ gb1,
    const float* __restrict__ gW2, const float* __restrict__ gb2,
    const float* __restrict__ mW1, const float* __restrict__ mb1,
    const float* __restrict__ mW2, const float* __restrict__ mb2,
    float* __restrict__ out, int B){
  int b = blockIdx.x, tid = threadIdx.x;
  __shared__ float qs[256];

  if (STEP > 0){
    if (tid < 128){
      const float* rs = rsum + (size_t)(STEP-1)*B*128 + (size_t)b*128;
      float ls = lsum[(STEP-1)*B + b];
      qs[tid]     = qbuf[b*128+tid];
      qs[128+tid] = rs[tid] / (ls + 1e-16f);
    }
    __syncthreads();
  }

  if (STEP < 3){
    __shared__ float hs[128], gsh[512];
    if (STEP > 0){ if (tid<128) hs[tid] = hc[(size_t)b*128+tid]; }
    __syncthreads();
    #pragma unroll
    for (int p=0;p<2;p++){
      int j = tid + p*256;
      float a = bih[j] + bhh[j];
      if (STEP > 0){
        const float* wi = Wih + (size_t)j*256;
        for (int k=0;k<256;k+=4)
          a += qs[k]*wi[k] + qs[k+1]*wi[k+1] + qs[k+2]*wi[k+2] + qs[k+3]*wi[k+3];
        const float* wh = Whh + (size_t)j*128;
        for (int k=0;k<128;k+=4)
          a += hs[k]*wh[k] + hs[k+1]*wh[k+1] + hs[k+2]*wh[k+2] + hs[k+3]*wh[k+3];
      }
      gsh[j] = a;
    }
    __syncthreads();
    if (tid < 128){
      float cprev = (STEP==0) ? 0.f : hc[(size_t)(B+b)*128+tid];
      float ig = sigmoidf(gsh[tid]);
      float fg = sigmoidf(gsh[128+tid]);
      float gg = tanhf(gsh[256+tid]);
      float og = sigmoidf(gsh[384+tid]);
      float c2 = fg*cprev + ig*gg;
      float h2 = og*tanhf(c2);
      hc[(size_t)b*128+tid] = h2;
      hc[(size_t)(B+b)*128+tid] = c2;
      qbuf[b*128+tid] = h2;
    }
  } else {
    __shared__ float z[288], gf1[64], hid[128];
    z[tid] = qs[tid];
    if (tid < 64){
      float a = gb1[tid];
      for (int k=0;k<9;k++) a += gfeat[b*9+k]*gW1[k*64+tid];
      gf1[tid] = a>0.f ? a : 0.f;
    }
    __syncthreads();
    if (tid < 32){
      float a = gb2[tid];
      for (int k=0;k<64;k++) a += gf1[k]*gW2[k*32+tid];
      z[256+tid] = a;
    }
    __syncthreads();
    if (tid < 128){
      float a = mb1[tid];
      for (int k=0;k<288;k++) a += z[k]*mW1[(size_t)k*128+tid];
      hid[tid] = a>0.f ? a : 0.f;
    }
    __syncthreads();
    if (tid < 4){
      float a = mb2[tid];
      for (int k=0;k<128;k++) a += hid[k]*mW2[k*4+tid];
      out[b*4+tid] = a;
    }
  }
}

// ================================ launch ====================================
extern "C" void kernel_launch(void* const* d_in, const int* in_sizes, int n_in,
                              void* d_out, int out_size, void* d_ws, size_t ws_size,
                              hipStream_t stream) {
  const float* x     = (const float*)d_in[0];
  const int*   ei    = (const int*)d_in[1];
  const int*   batch = (const int*)d_in[2];
  const float* gfeat = (const float*)d_in[3];
  const float* W1    = (const float*)d_in[4];
  const float* as1   = (const float*)d_in[5];
  const float* ad1   = (const float*)d_in[6];
  const float* b1    = (const float*)d_in[7];
  const float* W2    = (const float*)d_in[8];
  const float* as2   = (const float*)d_in[9];
  const float* ad2   = (const float*)d_in[10];
  const float* b2    = (const float*)d_in[11];
  const float* W3    = (const float*)d_in[12];
  const float* as3   = (const float*)d_in[13];
  const float* ad3   = (const float*)d_in[14];
  const float* b3    = (const float*)d_in[15];
  const float* Wih   = (const float*)d_in[16];
  const float* Whh   = (const float*)d_in[17];
  const float* bih   = (const float*)d_in[18];
  const float* bhh   = (const float*)d_in[19];
  const float* gW1   = (const float*)d_in[20];
  const float* gb1   = (const float*)d_in[21];
  const float* gW2   = (const float*)d_in[22];
  const float* gb2   = (const float*)d_in[23];
  const float* mW1   = (const float*)d_in[24];
  const float* mb1   = (const float*)d_in[25];
  const float* mW2   = (const float*)d_in[26];
  const float* mb2   = (const float*)d_in[27];

  const int N = in_sizes[0]/128;   // 20000
  const int E = in_sizes[1]/2;     // 320000
  const int B = in_sizes[3]/9;     // 64
  const int Mpad = ((N + 127)/128)*128;   // 20096

  char* ws = (char*)d_ws;
  size_t off = 0;
  auto alloc = [&](size_t bytes)->char*{
    char* p = ws + off;
    off += (bytes + 255) & ~(size_t)255;
    return p;
  };
  float*    hbuf    = (float*)alloc((size_t)N*256*4);
  unsigned* xsplit  = (unsigned*)alloc((size_t)Mpad*128*4);   // [Mpad,256] bf16
  unsigned* ysplit1 = (unsigned*)alloc((size_t)Mpad*256*4);   // [Mpad,512] bf16
  unsigned* ysplit2 = (unsigned*)alloc((size_t)Mpad*256*4);   // [Mpad,512] bf16
  float*    ybuf    = (float*)alloc((size_t)N*128*4);         // layer-3 out
  unsigned* WT1     = (unsigned*)alloc((size_t)128*256*4);
  unsigned* WT2     = (unsigned*)alloc((size_t)256*256*4);
  unsigned* WT3     = (unsigned*)alloc((size_t)256*128*4);
  float* sbuf   = (float*)alloc((size_t)N*4*4);
  float* dbuf   = (float*)alloc((size_t)N*4*4);
  int*   counts = (int*)alloc((size_t)N*4);
  int*   offs   = (int*)alloc((size_t)(N+1)*4);
  int*   cursor = (int*)alloc((size_t)N*4);
  int*   csr    = (int*)alloc((size_t)E*4);
  int*   gstart = (int*)alloc((size_t)B*4);
  int*   gend   = (int*)alloc((size_t)B*4);
  float* hcbuf  = (float*)alloc((size_t)2*B*128*4);
  float* qbuf   = (float*)alloc((size_t)B*128*4);
  float* rsum   = (float*)alloc((size_t)3*B*128*4);
  float* lsum   = (float*)alloc((size_t)3*B*4);

  int npadints = (Mpad - N)*256;
  int nInit = max(max(N, 3*B*128), npadints);
  init_kernel<<<(nInit+255)/256, 256, 0, stream>>>(counts, gstart, gend,
      rsum, lsum, (int*)(ysplit1 + (size_t)N*256), (int*)(ysplit2 + (size_t)N*256),
      npadints, N, B);
  int gridEN = (max(E,N)+255)/256;
  build_kernel<<<gridEN, 256, 0, stream>>>(ei, batch, counts, gstart, gend, E, N);
  scan_kernel<<<1, 1024, 0, stream>>>(counts, offs, cursor, N);
  fill_kernel<<<(E+255)/256, 256, 0, stream>>>(ei, cursor, csr, E);

  // conversions (single launch)
  int ncv = Mpad*128 + 128*256 + 256*256 + 256*128;
  convert_all<<<(ncv+255)/256, 256, 0, stream>>>(x, xsplit, N, Mpad,
                                                 W1, WT1, W2, WT2, W3, WT3);

  int gm = Mpad/64;   // 314 row-blocks
  // ---- layer 1: x -> h[N,256] -> ysplit1
  gemm_bf16<<<dim3(gm,2), 256, 0, stream>>>((const short*)xsplit, (const short*)WT1, hbuf, N, 256, 256);
  sd_kernel<4,64><<<(N+3)/4, 256, 0, stream>>>(hbuf, as1, ad1, sbuf, dbuf, N);
  agg_kernel<4,64,true><<<N, 256, 0, stream>>>(hbuf, sbuf, dbuf, offs, csr, b1, nullptr, ysplit1, N);
  // ---- layer 2: ysplit1 -> h[N,256] -> ysplit2
  gemm_bf16<<<dim3(gm,2), 256, 0, stream>>>((const short*)ysplit1, (const short*)WT2, hbuf, N, 512, 256);
  sd_kernel<4,64><<<(N+3)/4, 256, 0, stream>>>(hbuf, as2, ad2, sbuf, dbuf, N);
  agg_kernel<4,64,true><<<N, 256, 0, stream>>>(hbuf, sbuf, dbuf, offs, csr, b2, nullptr, ysplit2, N);
  // ---- layer 3: ysplit2 -> h[N,128] -> ybuf (fp32, feeds set2set)
  gemm_bf16<<<dim3(gm,1), 256, 0, stream>>>((const short*)ysplit2, (const short*)WT3, hbuf, N, 512, 128);
  sd_kernel<1,128><<<(N+3)/4, 256, 0, stream>>>(hbuf, as3, ad3, sbuf, dbuf, N);
  agg_kernel<1,128,false><<<N, 256, 0, stream>>>(hbuf, sbuf, dbuf, offs, csr, b3, ybuf, nullptr, N);

  // ---- set2set (fused grid-parallel readout) + scorer ----
  int gr = (N+31)/32;
  s2s_step_kernel<0><<<B, 256, 0, stream>>>(rsum, lsum, hcbuf, qbuf,
      Wih, Whh, bih, bhh, gfeat, gW1, gb1, gW2, gb2, mW1, mb1, mW2, mb2, (float*)d_out, B);
  read_kernel<<<gr, 256, 0, stream>>>(ybuf, qbuf, batch, rsum + 0*(size_t)B*128, lsum + 0*B, N);
  s2s_step_kernel<1><<<B, 256, 0, stream>>>(rsum, lsum, hcbuf, qbuf,
      Wih, Whh, bih, bhh, gfeat, gW1, gb1, gW2, gb2, mW1, mb1, mW2, mb2, (float*)d_out, B);
  read_kernel<<<gr, 256, 0, stream>>>(ybuf, qbuf, batch, rsum + 1*(size_t)B*128, lsum + 1*B, N);
  s2s_step_kernel<2><<<B, 256, 0, stream>>>(rsum, lsum, hcbuf, qbuf,
      Wih, Whh, bih, bhh, gfeat, gW1, gb1, gW2, gb2, mW1, mb1, mW2, mb2, (float*)d_out, B);
  read_kernel<<<gr, 256, 0, stream>>>(ybuf, qbuf, batch, rsum + 2*(size_t)B*128, lsum + 2*B, N);
  s2s_step_kernel<3><<<B, 256, 0, stream>>>(rsum, lsum, hcbuf, qbuf,
      Wih, Whh, bih, bhh, gfeat, gW1, gb1, gW2, gb2, mW1, mb1, mW2, mb2, (float*)d_out, B);
}

// Round 9
// 531.909 us; speedup vs baseline: 1.0754x; 1.0661x over previous
//
#include <hip/hip_runtime.h>
#include <hip/hip_bf16.h>
#include <math.h>

#define NEG_SLOPE 0.2f

typedef __attribute__((ext_vector_type(8))) short bf16x8;
typedef __attribute__((ext_vector_type(4))) float f32x4;

__device__ __forceinline__ float sigmoidf(float x){ return 1.f/(1.f+expf(-x)); }

// pack v into (hi,lo) bf16 pair: hi=bf16(v), lo=bf16(v-hi); hi|lo<<16.
__device__ __forceinline__ unsigned pack_split(float v){
  __hip_bfloat16 hi = __float2bfloat16(v);
  float rem = v - __bfloat162float(hi);
  __hip_bfloat16 lo = __float2bfloat16(rem);
  unsigned short uh = __builtin_bit_cast(unsigned short, hi);
  unsigned short ul = __builtin_bit_cast(unsigned short, lo);
  return (unsigned)uh | ((unsigned)ul << 16);
}
__device__ __forceinline__ unsigned short bf16of(float v){
  __hip_bfloat16 h = __float2bfloat16(v);
  return __builtin_bit_cast(unsigned short, h);
}

// ============== init + CSR prep + weight packing (one launch) ===============
__global__ void init_kernel(int* counts, int* gstart, int* gend,
                            float* rsum, float* lsum,
                            int* pad1, int* pad2, int npadints,
                            const float* __restrict__ W1, unsigned* __restrict__ WT1,
                            const float* __restrict__ W2, unsigned* __restrict__ WT2,
                            const float* __restrict__ W3, unsigned* __restrict__ WT3,
                            int n, int b){
  int i = blockIdx.x*blockDim.x + threadIdx.x;
  if (i < n) counts[i] = 0;
  if (i < b){ gstart[i] = 0; gend[i] = 0; }
  if (i < 3*b*128) rsum[i] = 0.f;
  if (i < 3*b) lsum[i] = 0.f;
  if (i < npadints){ pad1[i] = 0; pad2[i] = 0; }
  if (i < 128*256){                 // W1 [128,256] -> WT1 [256][128] uints
    int k = i>>8, c = i&255;
    WT1[(size_t)c*128 + k] = pack_split(W1[i]);
  }
  if (i < 256*256){                 // W2 [256,256] -> WT2 [256][256]
    int k = i>>8, c = i&255;
    WT2[(size_t)c*256 + k] = pack_split(W2[i]);
  }
  if (i < 256*128){                 // W3 [256,128] -> WT3 [128][256]
    int k = i>>7, c = i&127;
    WT3[(size_t)c*256 + k] = pack_split(W3[i]);
  }
}

__global__ void build_kernel(const int* __restrict__ ei, const int* __restrict__ batch,
                             int* counts, int* gstart, int* gend, int E, int n){
  int i = blockIdx.x*blockDim.x + threadIdx.x;
  if (i < E) atomicAdd(&counts[ei[E+i]], 1);
  if (i < n){
    int b = batch[i];
    if (i == 0 || batch[i-1] != b) gstart[b] = i;
    if (i == n-1 || batch[i+1] != b) gend[b] = i+1;
  }
}

__global__ void scan_kernel(const int* __restrict__ counts, int* offs, int* cursor, int n){
  const int T = 1024;
  int tid = threadIdx.x;
  int chunk = (n + T - 1)/T;
  int base = tid*chunk;
  int local = 0;
  for (int i=0;i<chunk;i++){ int idx=base+i; if (idx<n) local += counts[idx]; }
  __shared__ int ss[T];
  ss[tid]=local; __syncthreads();
  for (int off=1; off<T; off<<=1){
    int v = (tid>=off)? ss[tid-off] : 0;
    __syncthreads();
    ss[tid]+=v;
    __syncthreads();
  }
  int run = ss[tid]-local;
  for (int i=0;i<chunk;i++){
    int idx=base+i;
    if (idx<n){ offs[idx]=run; cursor[idx]=run; run += counts[idx]; }
  }
  if (tid==T-1) offs[n]=run;
}

__global__ void fill_kernel(const int* __restrict__ ei, int* cursor, int* csr, int E){
  int i = blockIdx.x*blockDim.x + threadIdx.x;
  if (i<E){
    int dst = ei[E+i];
    int pos = atomicAdd(&cursor[dst],1);
    csr[pos] = ei[i];
  }
}

// ===================== bf16 MFMA GEMM (exact via split-K doubling) ==========
// C[M,N] = A x BT^T. 64x128 tile, 256 thr, register-prefetch double buffer:
// next k0's global loads issue right after the LDS-store barrier and their
// vmcnt drain hides under the MFMA+ds_read block. AF32: A is fp32 [M,Ktot/2],
// split-packed inline during staging (kills the x-convert round trip).
// Epilogue writes fp32 C (for sd / set2set) and plain-bf16 copy (for agg's
// random gather - halves the gather working set).
template<bool AF32>
__global__ __launch_bounds__(256) void gemm_bf16(
    const void* __restrict__ Aptr, const short* __restrict__ BT,
    float* __restrict__ C, unsigned short* __restrict__ Cb16,
    int M, int Ktot, int N){
  __shared__ short As[64][72];
  __shared__ short Bs[128][72];
  int tid = threadIdx.x;
  int wave = tid>>6, lane = tid&63;
  int quad = lane>>4, l16 = lane&15;
  int bm = blockIdx.x*64, bn = blockIdx.y*128;
  f32x4 acc[8];
  #pragma unroll
  for (int i=0;i<8;i++) acc[i] = (f32x4){0.f,0.f,0.f,0.f};
  int rr = tid>>3;          // 0..31
  int seg = (tid&7)*8;      // shorts
  int4 ra[2], rb[4];
  auto loadAB = [&](int k0){
    if (AF32){
      const float* A = (const float*)Aptr;
      int Kf = Ktot>>1;
      int fo = (k0+seg)>>1;
      #pragma unroll
      for (int p=0;p<2;p++){
        int row = bm + p*32 + rr;
        float4 v = make_float4(0.f,0.f,0.f,0.f);
        if (row < M) v = *(const float4*)(A + (size_t)row*Kf + fo);
        ra[p] = make_int4((int)pack_split(v.x),(int)pack_split(v.y),
                          (int)pack_split(v.z),(int)pack_split(v.w));
      }
    } else {
      const short* A = (const short*)Aptr;
      #pragma unroll
      for (int p=0;p<2;p++)
        ra[p] = *(const int4*)(A + (size_t)(bm + p*32 + rr)*Ktot + k0 + seg);
    }
    #pragma unroll
    for (int p=0;p<4;p++)
      rb[p] = *(const int4*)(BT + (size_t)(bn + p*32 + rr)*Ktot + k0 + seg);
  };
  loadAB(0);
  for (int k0=0; k0<Ktot; k0+=64){
    __syncthreads();
    #pragma unroll
    for (int p=0;p<2;p++) *(int4*)&As[p*32+rr][seg] = ra[p];
    #pragma unroll
    for (int p=0;p<4;p++) *(int4*)&Bs[p*32+rr][seg] = rb[p];
    __syncthreads();
    if (k0+64 < Ktot) loadAB(k0+64);   // prefetch; regs free (already stored)
    #pragma unroll
    for (int kk=0;kk<2;kk++){
      bf16x8 af = *(bf16x8*)&As[wave*16 + l16][kk*32 + quad*8];
      #pragma unroll
      for (int nf=0;nf<8;nf++){
        bf16x8 bfv = *(bf16x8*)&Bs[nf*16 + l16][kk*32 + quad*8];
        acc[nf] = __builtin_amdgcn_mfma_f32_16x16x32_bf16(af, bfv, acc[nf], 0,0,0);
      }
    }
  }
  // C/D layout: col=lane&15, row=quad*4+reg (m89/m91 verified)
  #pragma unroll
  for (int r=0;r<4;r++){
    int row = bm + wave*16 + quad*4 + r;
    if (row < M){
      #pragma unroll
      for (int nf=0;nf<8;nf++){
        float v = acc[nf][r];
        int col = bn + nf*16 + l16;
        C[(size_t)row*N + col] = v;
        Cb16[(size_t)row*N + col] = bf16of(v);
      }
    }
  }
}

// ============== per-node attention logits s,d = <h, a_src/a_dst> ============
template<int H, int C>
__global__ void sd_kernel(const float* __restrict__ h, const float* __restrict__ asrc,
                          const float* __restrict__ adst, float* __restrict__ s,
                          float* __restrict__ d, int n_nodes){
  constexpr int HC = H*C;            // 256 (H=4) or 128 (H=1)
  int wave = threadIdx.x >> 6, lane = threadIdx.x & 63;
  int n = blockIdx.x*4 + wave;
  if (n >= n_nodes) return;
  if (HC == 256){
    float4 hv = *reinterpret_cast<const float4*>(h + (size_t)n*256 + lane*4);
    float4 av = *reinterpret_cast<const float4*>(asrc + lane*4);
    float4 dv = *reinterpret_cast<const float4*>(adst + lane*4);
    float ps = hv.x*av.x + hv.y*av.y + hv.z*av.z + hv.w*av.w;
    float pd = hv.x*dv.x + hv.y*dv.y + hv.z*dv.z + hv.w*dv.w;
    #pragma unroll
    for (int off=1; off<16; off<<=1){ ps += __shfl_xor(ps,off); pd += __shfl_xor(pd,off); }
    if ((lane&15)==0){
      int head = lane>>4;
      s[n*4+head]=ps; d[n*4+head]=pd;
    }
  } else {
    if (lane < 32){
      float4 hv = *reinterpret_cast<const float4*>(h + (size_t)n*128 + lane*4);
      float4 av = *reinterpret_cast<const float4*>(asrc + lane*4);
      float4 dv = *reinterpret_cast<const float4*>(adst + lane*4);
      float ps = hv.x*av.x + hv.y*av.y + hv.z*av.z + hv.w*av.w;
      float pd = hv.x*dv.x + hv.y*dv.y + hv.z*dv.z + hv.w*dv.w;
      #pragma unroll
      for (int off=1; off<32; off<<=1){ ps += __shfl_xor(ps,off); pd += __shfl_xor(pd,off); }
      if (lane==0){ s[n]=ps; d[n]=pd; }
    }
  }
}

// ================= GAT aggregation: softmax over in-edges ====================
// Gathers the bf16 h-copy (half the bytes of fp32; agg was at the 8-XCD
// fetch-replication floor, so FETCH halves). Accumulation stays fp32.
template<int H, int C, bool SPLIT>
__global__ __launch_bounds__(256) void agg_kernel(
    const unsigned short* __restrict__ hb, const float* __restrict__ s,
    const float* __restrict__ d, const int* __restrict__ offs,
    const int* __restrict__ csr, const float* __restrict__ bias,
    float* __restrict__ yf, unsigned* __restrict__ ys, int n_nodes){
  constexpr int HC = H*C;
  constexpr int VEC = HC/64;            // 4 (H=4,C=64) or 2 (H=1,C=128)
  int n = blockIdx.x;
  int tid = threadIdx.x;
  int wave = tid>>6, lane = tid&63;
  __shared__ float sdst[H];
  __shared__ float sl[H];
  __shared__ float sw[64*H];
  __shared__ int ssrc[64];
  __shared__ float facc[4][HC];
  if (tid < H) sdst[tid] = d[n*H+tid];
  int start = offs[n];
  int cnt = offs[n+1]-start;
  int cnt1 = cnt+1;                      // + self loop
  __syncthreads();
  float acc[VEC] = {};
  float lp[H];
  #pragma unroll
  for (int h=0;h<H;h++) lp[h]=0.f;
  for (int base=0; base<cnt1; base+=64){
    int nchunk = min(64, cnt1-base);
    if (tid < nchunk){
      int i = base+tid;
      int src = (i==cnt) ? n : csr[start+i];
      ssrc[tid]=src;
      if (H == 4){
        float4 sv = *reinterpret_cast<const float4*>(s + (size_t)src*4);
        float ev[4] = {sv.x, sv.y, sv.z, sv.w};
        #pragma unroll
        for (int h=0;h<4;h++){
          float e = ev[h] + sdst[h];
          e = e>=0.f ? e : NEG_SLOPE*e;
          float w = expf(e);
          sw[tid*4+h]=w;
          lp[h]+=w;
        }
      } else {
        float e = s[src] + sdst[0];
        e = e>=0.f ? e : NEG_SLOPE*e;
        float w = expf(e);
        sw[tid]=w;
        lp[0]+=w;
      }
    }
    __syncthreads();
    for (int j=wave; j<nchunk; j+=4){
      int src = ssrc[j];
      const unsigned short* hp = hb + (size_t)src*HC + lane*VEC;
      if (VEC == 4){
        float wt = sw[j*H + (lane>>4)];
        int2 hv = *reinterpret_cast<const int2*>(hp);
        acc[0] += wt*__uint_as_float(((unsigned)hv.x & 0xFFFFu) << 16);
        acc[1] += wt*__uint_as_float((unsigned)hv.x & 0xFFFF0000u);
        acc[2] += wt*__uint_as_float(((unsigned)hv.y & 0xFFFFu) << 16);
        acc[3] += wt*__uint_as_float((unsigned)hv.y & 0xFFFF0000u);
      } else {
        float wt = sw[j];
        unsigned hv = *reinterpret_cast<const unsigned*>(hp);
        acc[0] += wt*__uint_as_float((hv & 0xFFFFu) << 16);
        acc[1] += wt*__uint_as_float(hv & 0xFFFF0000u);
      }
    }
    __syncthreads();
  }
  if (wave==0){
    #pragma unroll
    for (int off=32; off; off>>=1)
      #pragma unroll
      for (int h=0;h<H;h++) lp[h] += __shfl_down(lp[h],off);
    if (lane==0)
      #pragma unroll
      for (int h=0;h<H;h++) sl[h]=lp[h];
  }
  #pragma unroll
  for (int v=0;v<VEC;v++) facc[wave][lane*VEC+v] = acc[v];
  __syncthreads();
  if (tid < HC){
    float a = facc[0][tid]+facc[1][tid]+facc[2][tid]+facc[3][tid];
    int head = tid / C;
    float o = a/(sl[head]+1e-16f) + bias[tid];
    o = o>0.f ? o : expm1f(o);
    if (SPLIT){
      ys[(size_t)n*HC + tid] = pack_split(o);
    } else {
      yf[(size_t)n*HC + tid] = o;
    }
  }
}

// ======================= Set2Set, grid-parallel =============================
__global__ __launch_bounds__(256) void read_kernel(
    const float* __restrict__ x, const float* __restrict__ q,
    const int* __restrict__ batch,
    float* __restrict__ rsum, float* __restrict__ lsum, int N){
  int tid = threadIdx.x;
  int wave = tid>>6, lane = tid&63;
  int c0 = blockIdx.x*32;
  if (c0 >= N) return;
  __shared__ float ws[32];
  __shared__ int gb[32];
  if (tid < 32 && c0+tid < N) gb[tid] = batch[c0+tid];
  __syncthreads();
  #pragma unroll
  for (int j=0;j<8;j++){
    int k = wave*8 + j;
    int i = c0 + k;
    if (i < N){
      int g = gb[k];
      float2 xv = *reinterpret_cast<const float2*>(x + (size_t)i*128 + lane*2);
      float2 qv = *reinterpret_cast<const float2*>(q + (size_t)g*128 + lane*2);
      float p = xv.x*qv.x + xv.y*qv.y;
      #pragma unroll
      for (int off=32; off; off>>=1) p += __shfl_down(p, off);
      if (lane==0) ws[k] = expf(p);
    }
  }
  __syncthreads();
  if (tid < 128){
    int col = tid;
    int endi = min(c0+32, N);
    int curg = gb[0];
    float acc = 0.f, lacc = 0.f;
    for (int i=c0; i<endi; ++i){
      int g = gb[i-c0];
      if (g != curg){
        atomicAdd(&rsum[curg*128+col], acc);
        if (col==0) atomicAdd(&lsum[curg], lacc);
        acc = 0.f; lacc = 0.f; curg = g;
      }
      float w = ws[i-c0];
      acc += w * x[(size_t)i*128+col];
      lacc += w;
    }
    atomicAdd(&rsum[curg*128+col], acc);
    if (col==0) atomicAdd(&lsum[curg], lacc);
  }
}

template<int STEP>
__global__ __launch_bounds__(256) void s2s_step_kernel(
    const float* __restrict__ rsum, const float* __restrict__ lsum,
    float* __restrict__ hc, float* __restrict__ qbuf,
    const float* __restrict__ Wih, const float* __restrict__ Whh,
    const float* __restrict__ bih, const float* __restrict__ bhh,
    const float* __restrict__ gfeat,
    const float* __restrict__ gW1, const float* __restrict__ gb1,
    const float* __restrict__ gW2, const float* __restrict__ gb2,
    const float* __restrict__ mW1, const float* __restrict__ mb1,
    const float* __restrict__ mW2, const float* __restrict__ mb2,
    float* __restrict__ out, int B){
  int b = blockIdx.x, tid = threadIdx.x;
  __shared__ float qs[256];

  if (STEP > 0){
    if (tid < 128){
      const float* rs = rsum + (size_t)(STEP-1)*B*128 + (size_t)b*128;
      float ls = lsum[(STEP-1)*B + b];
      qs[tid]     = qbuf[b*128+tid];
      qs[128+tid] = rs[tid] / (ls + 1e-16f);
    }
    __syncthreads();
  }

  if (STEP < 3){
    __shared__ float hs[128], gsh[512];
    if (STEP > 0){ if (tid<128) hs[tid] = hc[(size_t)b*128+tid]; }
    __syncthreads();
    #pragma unroll
    for (int p=0;p<2;p++){
      int j = tid + p*256;
      float a = bih[j] + bhh[j];
      if (STEP > 0){
        const float* wi = Wih + (size_t)j*256;
        for (int k=0;k<256;k+=4)
          a += qs[k]*wi[k] + qs[k+1]*wi[k+1] + qs[k+2]*wi[k+2] + qs[k+3]*wi[k+3];
        const float* wh = Whh + (size_t)j*128;
        for (int k=0;k<128;k+=4)
          a += hs[k]*wh[k] + hs[k+1]*wh[k+1] + hs[k+2]*wh[k+2] + hs[k+3]*wh[k+3];
      }
      gsh[j] = a;
    }
    __syncthreads();
    if (tid < 128){
      float cprev = (STEP==0) ? 0.f : hc[(size_t)(B+b)*128+tid];
      float ig = sigmoidf(gsh[tid]);
      float fg = sigmoidf(gsh[128+tid]);
      float gg = tanhf(gsh[256+tid]);
      float og = sigmoidf(gsh[384+tid]);
      float c2 = fg*cprev + ig*gg;
      float h2 = og*tanhf(c2);
      hc[(size_t)b*128+tid] = h2;
      hc[(size_t)(B+b)*128+tid] = c2;
      qbuf[b*128+tid] = h2;
    }
  } else {
    __shared__ float z[288], gf1[64], hid[128];
    z[tid] = qs[tid];
    if (tid < 64){
      float a = gb1[tid];
      for (int k=0;k<9;k++) a += gfeat[b*9+k]*gW1[k*64+tid];
      gf1[tid] = a>0.f ? a : 0.f;
    }
    __syncthreads();
    if (tid < 32){
      float a = gb2[tid];
      for (int k=0;k<64;k++) a += gf1[k]*gW2[k*32+tid];
      z[256+tid] = a;
    }
    __syncthreads();
    if (tid < 128){
      float a = mb1[tid];
      for (int k=0;k<288;k++) a += z[k]*mW1[(size_t)k*128+tid];
      hid[tid] = a>0.f ? a : 0.f;
    }
    __syncthreads();
    if (tid < 4){
      float a = mb2[tid];
      for (int k=0;k<128;k++) a += hid[k]*mW2[k*4+tid];
      out[b*4+tid] = a;
    }
  }
}

// ================================ launch ====================================
extern "C" void kernel_launch(void* const* d_in, const int* in_sizes, int n_in,
                              void* d_out, int out_size, void* d_ws, size_t ws_size,
                              hipStream_t stream) {
  const float* x     = (const float*)d_in[0];
  const int*   ei    = (const int*)d_in[1];
  const int*   batch = (const int*)d_in[2];
  const float* gfeat = (const float*)d_in[3];
  const float* W1    = (const float*)d_in[4];
  const float* as1   = (const float*)d_in[5];
  const float* ad1   = (const float*)d_in[6];
  const float* b1    = (const float*)d_in[7];
  const float* W2    = (const float*)d_in[8];
  const float* as2   = (const float*)d_in[9];
  const float* ad2   = (const float*)d_in[10];
  const float* b2    = (const float*)d_in[11];
  const float* W3    = (const float*)d_in[12];
  const float* as3   = (const float*)d_in[13];
  const float* ad3   = (const float*)d_in[14];
  const float* b3    = (const float*)d_in[15];
  const float* Wih   = (const float*)d_in[16];
  const float* Whh   = (const float*)d_in[17];
  const float* bih   = (const float*)d_in[18];
  const float* bhh   = (const float*)d_in[19];
  const float* gW1   = (const float*)d_in[20];
  const float* gb1   = (const float*)d_in[21];
  const float* gW2   = (const float*)d_in[22];
  const float* gb2   = (const float*)d_in[23];
  const float* mW1   = (const float*)d_in[24];
  const float* mb1   = (const float*)d_in[25];
  const float* mW2   = (const float*)d_in[26];
  const float* mb2   = (const float*)d_in[27];

  const int N = in_sizes[0]/128;   // 20000
  const int E = in_sizes[1]/2;     // 320000
  const int B = in_sizes[3]/9;     // 64
  const int Mpad = ((N + 127)/128)*128;   // 20096

  char* ws = (char*)d_ws;
  size_t off = 0;
  auto alloc = [&](size_t bytes)->char*{
    char* p = ws + off;
    off += (bytes + 255) & ~(size_t)255;
    return p;
  };
  float*    hbuf    = (float*)alloc((size_t)N*256*4);
  unsigned short* hb16 = (unsigned short*)alloc((size_t)N*256*2);   // bf16 h copy
  unsigned* ysplit1 = (unsigned*)alloc((size_t)Mpad*256*4);
  unsigned* ysplit2 = (unsigned*)alloc((size_t)Mpad*256*4);
  float*    ybuf    = (float*)alloc((size_t)N*128*4);
  unsigned* WT1     = (unsigned*)alloc((size_t)256*128*4);
  unsigned* WT2     = (unsigned*)alloc((size_t)256*256*4);
  unsigned* WT3     = (unsigned*)alloc((size_t)128*256*4);
  float* sbuf   = (float*)alloc((size_t)N*4*4);
  float* dbuf   = (float*)alloc((size_t)N*4*4);
  int*   counts = (int*)alloc((size_t)N*4);
  int*   offs   = (int*)alloc((size_t)(N+1)*4);
  int*   cursor = (int*)alloc((size_t)N*4);
  int*   csr    = (int*)alloc((size_t)E*4);
  int*   gstart = (int*)alloc((size_t)B*4);
  int*   gend   = (int*)alloc((size_t)B*4);
  float* hcbuf  = (float*)alloc((size_t)2*B*128*4);
  float* qbuf   = (float*)alloc((size_t)B*128*4);
  float* rsum   = (float*)alloc((size_t)3*B*128*4);
  float* lsum   = (float*)alloc((size_t)3*B*4);

  int npadints = (Mpad - N)*256;
  int nInit = max(max(N, npadints), 256*256);
  init_kernel<<<(nInit+255)/256, 256, 0, stream>>>(counts, gstart, gend,
      rsum, lsum, (int*)(ysplit1 + (size_t)N*256), (int*)(ysplit2 + (size_t)N*256),
      npadints, W1, WT1, W2, WT2, W3, WT3, N, B);
  int gridEN = (max(E,N)+255)/256;
  build_kernel<<<gridEN, 256, 0, stream>>>(ei, batch, counts, gstart, gend, E, N);
  scan_kernel<<<1, 1024, 0, stream>>>(counts, offs, cursor, N);
  fill_kernel<<<(E+255)/256, 256, 0, stream>>>(ei, cursor, csr, E);

  int gm = Mpad/64;
  // ---- layer 1: x (fp32, inline split) -> h[N,256] -> ysplit1
  gemm_bf16<true><<<dim3(gm,2), 256, 0, stream>>>((const void*)x, (const short*)WT1,
                                                  hbuf, hb16, N, 256, 256);
  sd_kernel<4,64><<<(N+3)/4, 256, 0, stream>>>(hbuf, as1, ad1, sbuf, dbuf, N);
  agg_kernel<4,64,true><<<N, 256, 0, stream>>>(hb16, sbuf, dbuf, offs, csr, b1, nullptr, ysplit1, N);
  // ---- layer 2: ysplit1 -> h[N,256] -> ysplit2
  gemm_bf16<false><<<dim3(gm,2), 256, 0, stream>>>((const void*)ysplit1, (const short*)WT2,
                                                   hbuf, hb16, N, 512, 256);
  sd_kernel<4,64><<<(N+3)/4, 256, 0, stream>>>(hbuf, as2, ad2, sbuf, dbuf, N);
  agg_kernel<4,64,true><<<N, 256, 0, stream>>>(hb16, sbuf, dbuf, offs, csr, b2, nullptr, ysplit2, N);
  // ---- layer 3: ysplit2 -> h[N,128] -> ybuf (fp32, feeds set2set)
  gemm_bf16<false><<<dim3(gm,1), 256, 0, stream>>>((const void*)ysplit2, (const short*)WT3,
                                                   hbuf, hb16, N, 512, 128);
  sd_kernel<1,128><<<(N+3)/4, 256, 0, stream>>>(hbuf, as3, ad3, sbuf, dbuf, N);
  agg_kernel<1,128,false><<<N, 256, 0, stream>>>(hb16, sbuf, dbuf, offs, csr, b3, ybuf, nullptr, N);

  // ---- set2set (fused grid-parallel readout) + scorer ----
  int gr = (N+31)/32;
  s2s_step_kernel<0><<<B, 256, 0, stream>>>(rsum, lsum, hcbuf, qbuf,
      Wih, Whh, bih, bhh, gfeat, gW1, gb1, gW2, gb2, mW1, mb1, mW2, mb2, (float*)d_out, B);
  read_kernel<<<gr, 256, 0, stream>>>(ybuf, qbuf, batch, rsum + 0*(size_t)B*128, lsum + 0*B, N);
  s2s_step_kernel<1><<<B, 256, 0, stream>>>(rsum, lsum, hcbuf, qbuf,
      Wih, Whh, bih, bhh, gfeat, gW1, gb1, gW2, gb2, mW1, mb1, mW2, mb2, (float*)d_out, B);
  read_kernel<<<gr, 256, 0, stream>>>(ybuf, qbuf, batch, rsum + 1*(size_t)B*128, lsum + 1*B, N);
  s2s_step_kernel<2><<<B, 256, 0, stream>>>(rsum, lsum, hcbuf, qbuf,
      Wih, Whh, bih, bhh, gfeat, gW1, gb1, gW2, gb2, mW1, mb1, mW2, mb2, (float*)d_out, B);
  read_kernel<<<gr, 256, 0, stream>>>(ybuf, qbuf, batch, rsum + 2*(size_t)B*128, lsum + 2*B, N);
  s2s_step_kernel<3><<<B, 256, 0, stream>>>(rsum, lsum, hcbuf, qbuf,
      Wih, Whh, bih, bhh, gfeat, gW1, gb1, gW2, gb2, mW1, mb1, mW2, mb2, (float*)d_out, B);
}

// Round 10
// 526.802 us; speedup vs baseline: 1.0858x; 1.0097x over previous
//
#include <hip/hip_runtime.h>
#include <hip/hip_bf16.h>
#include <math.h>

#define NEG_SLOPE 0.2f

typedef __attribute__((ext_vector_type(8))) short bf16x8;
typedef __attribute__((ext_vector_type(4))) float f32x4;

__device__ __forceinline__ float sigmoidf(float x){ return 1.f/(1.f+expf(-x)); }
__device__ __forceinline__ float bf2f(unsigned us){ return __uint_as_float(us << 16); }

// pack v into (hi,lo) bf16 pair: hi=bf16(v), lo=bf16(v-hi); hi|lo<<16.
__device__ __forceinline__ unsigned pack_split(float v){
  __hip_bfloat16 hi = __float2bfloat16(v);
  float rem = v - __bfloat162float(hi);
  __hip_bfloat16 lo = __float2bfloat16(rem);
  unsigned short uh = __builtin_bit_cast(unsigned short, hi);
  unsigned short ul = __builtin_bit_cast(unsigned short, lo);
  return (unsigned)uh | ((unsigned)ul << 16);
}
__device__ __forceinline__ unsigned short bf16of(float v){
  __hip_bfloat16 h = __float2bfloat16(v);
  return __builtin_bit_cast(unsigned short, h);
}

// ============== init + CSR prep + weight packing (one launch) ===============
__global__ void init_kernel(int* counts, int* gstart, int* gend,
                            float* rsum, float* lsum,
                            int* pad1, int* pad2, int npadints,
                            const float* __restrict__ W1, unsigned* __restrict__ WT1,
                            const float* __restrict__ W2, unsigned* __restrict__ WT2,
                            const float* __restrict__ W3, unsigned* __restrict__ WT3,
                            int n, int b){
  int i = blockIdx.x*blockDim.x + threadIdx.x;
  if (i < n) counts[i] = 0;
  if (i < b){ gstart[i] = 0; gend[i] = 0; }
  if (i < 3*b*128) rsum[i] = 0.f;
  if (i < 3*b) lsum[i] = 0.f;
  if (i < npadints){ pad1[i] = 0; pad2[i] = 0; }
  if (i < 128*256){                 // W1 [128,256] -> WT1 [256][128] uints
    int k = i>>8, c = i&255;
    WT1[(size_t)c*128 + k] = pack_split(W1[i]);
  }
  if (i < 256*256){                 // W2 [256,256] -> WT2 [256][256]
    int k = i>>8, c = i&255;
    WT2[(size_t)c*256 + k] = pack_split(W2[i]);
  }
  if (i < 256*128){                 // W3 [256,128] -> WT3 [128][256]
    int k = i>>7, c = i&127;
    WT3[(size_t)c*256 + k] = pack_split(W3[i]);
  }
}

__global__ void build_kernel(const int* __restrict__ ei, const int* __restrict__ batch,
                             int* counts, int* gstart, int* gend, int E, int n){
  int i = blockIdx.x*blockDim.x + threadIdx.x;
  if (i < E) atomicAdd(&counts[ei[E+i]], 1);
  if (i < n){
    int b = batch[i];
    if (i == 0 || batch[i-1] != b) gstart[b] = i;
    if (i == n-1 || batch[i+1] != b) gend[b] = i+1;
  }
}

__global__ void scan_kernel(const int* __restrict__ counts, int* offs, int* cursor, int n){
  const int T = 1024;
  int tid = threadIdx.x;
  int chunk = (n + T - 1)/T;
  int base = tid*chunk;
  int local = 0;
  for (int i=0;i<chunk;i++){ int idx=base+i; if (idx<n) local += counts[idx]; }
  __shared__ int ss[T];
  ss[tid]=local; __syncthreads();
  for (int off=1; off<T; off<<=1){
    int v = (tid>=off)? ss[tid-off] : 0;
    __syncthreads();
    ss[tid]+=v;
    __syncthreads();
  }
  int run = ss[tid]-local;
  for (int i=0;i<chunk;i++){
    int idx=base+i;
    if (idx<n){ offs[idx]=run; cursor[idx]=run; run += counts[idx]; }
  }
  if (tid==T-1) offs[n]=run;
}

__global__ void fill_kernel(const int* __restrict__ ei, int* cursor, int* csr, int E){
  int i = blockIdx.x*blockDim.x + threadIdx.x;
  if (i<E){
    int dst = ei[E+i];
    int pos = atomicAdd(&cursor[dst],1);
    csr[pos] = ei[i];
  }
}

// ===================== bf16 MFMA GEMM (exact via split-K doubling) ==========
// C[M,N] = A x BT^T, output ONLY as plain bf16 (all consumers - sd gather,
// agg gather - read bf16; the fp32 C was 2/3 of the write traffic and its
// scattered stores amplified WRITE_SIZE 3.3x). Epilogue stages each wave's
// 4-row group in private LDS and writes full 256B row segments (coalesced).
// bm from blockIdx.y, bn from blockIdx.x so the bn-pair sharing an A tile is
// dispatch-adjacent (L2 catches the A re-fetch).
template<bool AF32>
__global__ __launch_bounds__(256) void gemm_bf16(
    const void* __restrict__ Aptr, const short* __restrict__ BT,
    unsigned short* __restrict__ Cb16, int M, int Ktot, int N){
  __shared__ short As[64][72];
  __shared__ short Bs[128][72];
  int tid = threadIdx.x;
  int wave = tid>>6, lane = tid&63;
  int quad = lane>>4, l16 = lane&15;
  int bm = blockIdx.y*64, bn = blockIdx.x*128;
  f32x4 acc[8];
  #pragma unroll
  for (int i=0;i<8;i++) acc[i] = (f32x4){0.f,0.f,0.f,0.f};
  int rr = tid>>3;          // 0..31
  int seg = (tid&7)*8;      // shorts
  int4 ra[2], rb[4];
  auto loadAB = [&](int k0){
    if (AF32){
      const float* A = (const float*)Aptr;
      int Kf = Ktot>>1;
      int fo = (k0+seg)>>1;
      #pragma unroll
      for (int p=0;p<2;p++){
        int row = bm + p*32 + rr;
        float4 v = make_float4(0.f,0.f,0.f,0.f);
        if (row < M) v = *(const float4*)(A + (size_t)row*Kf + fo);
        ra[p] = make_int4((int)pack_split(v.x),(int)pack_split(v.y),
                          (int)pack_split(v.z),(int)pack_split(v.w));
      }
    } else {
      const short* A = (const short*)Aptr;
      #pragma unroll
      for (int p=0;p<2;p++)
        ra[p] = *(const int4*)(A + (size_t)(bm + p*32 + rr)*Ktot + k0 + seg);
    }
    #pragma unroll
    for (int p=0;p<4;p++)
      rb[p] = *(const int4*)(BT + (size_t)(bn + p*32 + rr)*Ktot + k0 + seg);
  };
  loadAB(0);
  for (int k0=0; k0<Ktot; k0+=64){
    __syncthreads();
    #pragma unroll
    for (int p=0;p<2;p++) *(int4*)&As[p*32+rr][seg] = ra[p];
    #pragma unroll
    for (int p=0;p<4;p++) *(int4*)&Bs[p*32+rr][seg] = rb[p];
    __syncthreads();
    if (k0+64 < Ktot) loadAB(k0+64);   // prefetch; regs free (already stored)
    #pragma unroll
    for (int kk=0;kk<2;kk++){
      bf16x8 af = *(bf16x8*)&As[wave*16 + l16][kk*32 + quad*8];
      #pragma unroll
      for (int nf=0;nf<8;nf++){
        bf16x8 bfv = *(bf16x8*)&Bs[nf*16 + l16][kk*32 + quad*8];
        acc[nf] = __builtin_amdgcn_mfma_f32_16x16x32_bf16(af, bfv, acc[nf], 0,0,0);
      }
    }
  }
  // ---- coalesced bf16 epilogue via LDS staging ----
  // C/D layout: col=lane&15, row=quad*4+reg (m89/m91 verified)
  __syncthreads();                       // all frag reads done; reuse As
  unsigned short* stg = (unsigned short*)(&As[0][0]) + wave*528;  // 4x132 shorts
  #pragma unroll
  for (int r=0;r<4;r++){
    #pragma unroll
    for (int nf=0;nf<8;nf++)
      stg[quad*132 + nf*16 + l16] = bf16of(acc[nf][r]);
    #pragma unroll
    for (int p=0;p<4;p++){
      int row = bm + wave*16 + p*4 + r;
      if (row < M){
        unsigned v = (unsigned)stg[p*132 + lane*2] |
                     ((unsigned)stg[p*132 + lane*2 + 1] << 16);
        *(unsigned*)(Cb16 + (size_t)row*N + bn + lane*2) = v;
      }
    }
  }
}

// ============== per-node attention logits s,d = <h, a_src/a_dst> ============
// Reads the bf16 h array (the only copy). One wave per node, coalesced.
template<int H, int C>
__global__ void sd_kernel(const unsigned short* __restrict__ hb,
                          const float* __restrict__ asrc,
                          const float* __restrict__ adst, float* __restrict__ s,
                          float* __restrict__ d, int n_nodes){
  int wave = threadIdx.x >> 6, lane = threadIdx.x & 63;
  int n = blockIdx.x*4 + wave;
  if (n >= n_nodes) return;
  if (H == 4){
    uint2 u = *reinterpret_cast<const uint2*>(hb + (size_t)n*256 + lane*4);
    float4 av = *reinterpret_cast<const float4*>(asrc + lane*4);
    float4 dv = *reinterpret_cast<const float4*>(adst + lane*4);
    float h0 = bf2f(u.x & 0xFFFFu), h1 = bf2f(u.x >> 16);
    float h2 = bf2f(u.y & 0xFFFFu), h3 = bf2f(u.y >> 16);
    float ps = h0*av.x + h1*av.y + h2*av.z + h3*av.w;
    float pd = h0*dv.x + h1*dv.y + h2*dv.z + h3*dv.w;
    #pragma unroll
    for (int off=1; off<16; off<<=1){ ps += __shfl_xor(ps,off); pd += __shfl_xor(pd,off); }
    if ((lane&15)==0){
      int head = lane>>4;
      s[n*4+head]=ps; d[n*4+head]=pd;
    }
  } else {
    unsigned u = *reinterpret_cast<const unsigned*>(hb + (size_t)n*128 + lane*2);
    float2 av = *reinterpret_cast<const float2*>(asrc + lane*2);
    float2 dv = *reinterpret_cast<const float2*>(adst + lane*2);
    float h0 = bf2f(u & 0xFFFFu), h1 = bf2f(u >> 16);
    float ps = h0*av.x + h1*av.y;
    float pd = h0*dv.x + h1*dv.y;
    #pragma unroll
    for (int off=1; off<64; off<<=1){ ps += __shfl_xor(ps,off); pd += __shfl_xor(pd,off); }
    if (lane==0){ s[n]=ps; d[n]=pd; }
  }
}

// ================= GAT aggregation: softmax over in-edges ====================
template<int H, int C, bool SPLIT>
__global__ __launch_bounds__(256) void agg_kernel(
    const unsigned short* __restrict__ hb, const float* __restrict__ s,
    const float* __restrict__ d, const int* __restrict__ offs,
    const int* __restrict__ csr, const float* __restrict__ bias,
    float* __restrict__ yf, unsigned* __restrict__ ys, int n_nodes){
  constexpr int HC = H*C;
  constexpr int VEC = HC/64;            // 4 (H=4,C=64) or 2 (H=1,C=128)
  int n = blockIdx.x;
  int tid = threadIdx.x;
  int wave = tid>>6, lane = tid&63;
  __shared__ float sdst[H];
  __shared__ float sl[H];
  __shared__ float sw[64*H];
  __shared__ int ssrc[64];
  __shared__ float facc[4][HC];
  if (tid < H) sdst[tid] = d[n*H+tid];
  int start = offs[n];
  int cnt = offs[n+1]-start;
  int cnt1 = cnt+1;                      // + self loop
  __syncthreads();
  float acc[VEC] = {};
  float lp[H];
  #pragma unroll
  for (int h=0;h<H;h++) lp[h]=0.f;
  for (int base=0; base<cnt1; base+=64){
    int nchunk = min(64, cnt1-base);
    if (tid < nchunk){
      int i = base+tid;
      int src = (i==cnt) ? n : csr[start+i];
      ssrc[tid]=src;
      if (H == 4){
        float4 sv = *reinterpret_cast<const float4*>(s + (size_t)src*4);
        float ev[4] = {sv.x, sv.y, sv.z, sv.w};
        #pragma unroll
        for (int h=0;h<4;h++){
          float e = ev[h] + sdst[h];
          e = e>=0.f ? e : NEG_SLOPE*e;
          float w = expf(e);
          sw[tid*4+h]=w;
          lp[h]+=w;
        }
      } else {
        float e = s[src] + sdst[0];
        e = e>=0.f ? e : NEG_SLOPE*e;
        float w = expf(e);
        sw[tid]=w;
        lp[0]+=w;
      }
    }
    __syncthreads();
    for (int j=wave; j<nchunk; j+=4){
      int src = ssrc[j];
      const unsigned short* hp = hb + (size_t)src*HC + lane*VEC;
      if (VEC == 4){
        float wt = sw[j*H + (lane>>4)];
        int2 hv = *reinterpret_cast<const int2*>(hp);
        acc[0] += wt*bf2f((unsigned)hv.x & 0xFFFFu);
        acc[1] += wt*bf2f((unsigned)hv.x >> 16);
        acc[2] += wt*bf2f((unsigned)hv.y & 0xFFFFu);
        acc[3] += wt*bf2f((unsigned)hv.y >> 16);
      } else {
        float wt = sw[j];
        unsigned hv = *reinterpret_cast<const unsigned*>(hp);
        acc[0] += wt*bf2f(hv & 0xFFFFu);
        acc[1] += wt*bf2f(hv >> 16);
      }
    }
    __syncthreads();
  }
  if (wave==0){
    #pragma unroll
    for (int off=32; off; off>>=1)
      #pragma unroll
      for (int h=0;h<H;h++) lp[h] += __shfl_down(lp[h],off);
    if (lane==0)
      #pragma unroll
      for (int h=0;h<H;h++) sl[h]=lp[h];
  }
  #pragma unroll
  for (int v=0;v<VEC;v++) facc[wave][lane*VEC+v] = acc[v];
  __syncthreads();
  if (tid < HC){
    float a = facc[0][tid]+facc[1][tid]+facc[2][tid]+facc[3][tid];
    int head = tid / C;
    float o = a/(sl[head]+1e-16f) + bias[tid];
    o = o>0.f ? o : expm1f(o);
    if (SPLIT){
      ys[(size_t)n*HC + tid] = pack_split(o);
    } else {
      yf[(size_t)n*HC + tid] = o;
    }
  }
}

// ======================= Set2Set, grid-parallel =============================
__global__ __launch_bounds__(256) void read_kernel(
    const float* __restrict__ x, const float* __restrict__ q,
    const int* __restrict__ batch,
    float* __restrict__ rsum, float* __restrict__ lsum, int N){
  int tid = threadIdx.x;
  int wave = tid>>6, lane = tid&63;
  int c0 = blockIdx.x*32;
  if (c0 >= N) return;
  __shared__ float ws[32];
  __shared__ int gb[32];
  if (tid < 32 && c0+tid < N) gb[tid] = batch[c0+tid];
  __syncthreads();
  #pragma unroll
  for (int j=0;j<8;j++){
    int k = wave*8 + j;
    int i = c0 + k;
    if (i < N){
      int g = gb[k];
      float2 xv = *reinterpret_cast<const float2*>(x + (size_t)i*128 + lane*2);
      float2 qv = *reinterpret_cast<const float2*>(q + (size_t)g*128 + lane*2);
      float p = xv.x*qv.x + xv.y*qv.y;
      #pragma unroll
      for (int off=32; off; off>>=1) p += __shfl_down(p, off);
      if (lane==0) ws[k] = expf(p);
    }
  }
  __syncthreads();
  if (tid < 128){
    int col = tid;
    int endi = min(c0+32, N);
    int curg = gb[0];
    float acc = 0.f, lacc = 0.f;
    for (int i=c0; i<endi; ++i){
      int g = gb[i-c0];
      if (g != curg){
        atomicAdd(&rsum[curg*128+col], acc);
        if (col==0) atomicAdd(&lsum[curg], lacc);
        acc = 0.f; lacc = 0.f; curg = g;
      }
      float w = ws[i-c0];
      acc += w * x[(size_t)i*128+col];
      lacc += w;
    }
    atomicAdd(&rsum[curg*128+col], acc);
    if (col==0) atomicAdd(&lsum[curg], lacc);
  }
}

template<int STEP>
__global__ __launch_bounds__(256) void s2s_step_kernel(
    const float* __restrict__ rsum, const float* __restrict__ lsum,
    float* __restrict__ hc, float* __restrict__ qbuf,
    const float* __restrict__ Wih, const float* __restrict__ Whh,
    const float* __restrict__ bih, const float* __restrict__ bhh,
    const float* __restrict__ gfeat,
    const float* __restrict__ gW1, const float* __restrict__ gb1,
    const float* __restrict__ gW2, const float* __restrict__ gb2,
    const float* __restrict__ mW1, const float* __restrict__ mb1,
    const float* __restrict__ mW2, const float* __restrict__ mb2,
    float* __restrict__ out, int B){
  int b = blockIdx.x, tid = threadIdx.x;
  __shared__ float qs[256];

  if (STEP > 0){
    if (tid < 128){
      const float* rs = rsum + (size_t)(STEP-1)*B*128 + (size_t)b*128;
      float ls = lsum[(STEP-1)*B + b];
      qs[tid]     = qbuf[b*128+tid];
      qs[128+tid] = rs[tid] / (ls + 1e-16f);
    }
    __syncthreads();
  }

  if (STEP < 3){
    __shared__ float hs[128], gsh[512];
    if (STEP > 0){ if (tid<128) hs[tid] = hc[(size_t)b*128+tid]; }
    __syncthreads();
    #pragma unroll
    for (int p=0;p<2;p++){
      int j = tid + p*256;
      float a = bih[j] + bhh[j];
      if (STEP > 0){
        const float* wi = Wih + (size_t)j*256;
        for (int k=0;k<256;k+=4)
          a += qs[k]*wi[k] + qs[k+1]*wi[k+1] + qs[k+2]*wi[k+2] + qs[k+3]*wi[k+3];
        const float* wh = Whh + (size_t)j*128;
        for (int k=0;k<128;k+=4)
          a += hs[k]*wh[k] + hs[k+1]*wh[k+1] + hs[k+2]*wh[k+2] + hs[k+3]*wh[k+3];
      }
      gsh[j] = a;
    }
    __syncthreads();
    if (tid < 128){
      float cprev = (STEP==0) ? 0.f : hc[(size_t)(B+b)*128+tid];
      float ig = sigmoidf(gsh[tid]);
      float fg = sigmoidf(gsh[128+tid]);
      float gg = tanhf(gsh[256+tid]);
      float og = sigmoidf(gsh[384+tid]);
      float c2 = fg*cprev + ig*gg;
      float h2 = og*tanhf(c2);
      hc[(size_t)b*128+tid] = h2;
      hc[(size_t)(B+b)*128+tid] = c2;
      qbuf[b*128+tid] = h2;
    }
  } else {
    __shared__ float z[288], gf1[64], hid[128];
    z[tid] = qs[tid];
    if (tid < 64){
      float a = gb1[tid];
      for (int k=0;k<9;k++) a += gfeat[b*9+k]*gW1[k*64+tid];
      gf1[tid] = a>0.f ? a : 0.f;
    }
    __syncthreads();
    if (tid < 32){
      float a = gb2[tid];
      for (int k=0;k<64;k++) a += gf1[k]*gW2[k*32+tid];
      z[256+tid] = a;
    }
    __syncthreads();
    if (tid < 128){
      float a = mb1[tid];
      for (int k=0;k<288;k++) a += z[k]*mW1[(size_t)k*128+tid];
      hid[tid] = a>0.f ? a : 0.f;
    }
    __syncthreads();
    if (tid < 4){
      float a = mb2[tid];
      for (int k=0;k<128;k++) a += hid[k]*mW2[k*4+tid];
      out[b*4+tid] = a;
    }
  }
}

// ================================ launch ====================================
extern "C" void kernel_launch(void* const* d_in, const int* in_sizes, int n_in,
                              void* d_out, int out_size, void* d_ws, size_t ws_size,
                              hipStream_t stream) {
  const float* x     = (const float*)d_in[0];
  const int*   ei    = (const int*)d_in[1];
  const int*   batch = (const int*)d_in[2];
  const float* gfeat = (const float*)d_in[3];
  const float* W1    = (const float*)d_in[4];
  const float* as1   = (const float*)d_in[5];
  const float* ad1   = (const float*)d_in[6];
  const float* b1    = (const float*)d_in[7];
  const float* W2    = (const float*)d_in[8];
  const float* as2   = (const float*)d_in[9];
  const float* ad2   = (const float*)d_in[10];
  const float* b2    = (const float*)d_in[11];
  const float* W3    = (const float*)d_in[12];
  const float* as3   = (const float*)d_in[13];
  const float* ad3   = (const float*)d_in[14];
  const float* b3    = (const float*)d_in[15];
  const float* Wih   = (const float*)d_in[16];
  const float* Whh   = (const float*)d_in[17];
  const float* bih   = (const float*)d_in[18];
  const float* bhh   = (const float*)d_in[19];
  const float* gW1   = (const float*)d_in[20];
  const float* gb1   = (const float*)d_in[21];
  const float* gW2   = (const float*)d_in[22];
  const float* gb2   = (const float*)d_in[23];
  const float* mW1   = (const float*)d_in[24];
  const float* mb1   = (const float*)d_in[25];
  const float* mW2   = (const float*)d_in[26];
  const float* mb2   = (const float*)d_in[27];

  const int N = in_sizes[0]/128;   // 20000
  const int E = in_sizes[1]/2;     // 320000
  const int B = in_sizes[3]/9;     // 64
  const int Mpad = ((N + 127)/128)*128;   // 20096

  char* ws = (char*)d_ws;
  size_t off = 0;
  auto alloc = [&](size_t bytes)->char*{
    char* p = ws + off;
    off += (bytes + 255) & ~(size_t)255;
    return p;
  };
  unsigned short* hb16 = (unsigned short*)alloc((size_t)N*256*2);   // bf16 h
  unsigned* ysplit1 = (unsigned*)alloc((size_t)Mpad*256*4);
  unsigned* ysplit2 = (unsigned*)alloc((size_t)Mpad*256*4);
  float*    ybuf    = (float*)alloc((size_t)N*128*4);
  unsigned* WT1     = (unsigned*)alloc((size_t)256*128*4);
  unsigned* WT2     = (unsigned*)alloc((size_t)256*256*4);
  unsigned* WT3     = (unsigned*)alloc((size_t)128*256*4);
  float* sbuf   = (float*)alloc((size_t)N*4*4);
  float* dbuf   = (float*)alloc((size_t)N*4*4);
  int*   counts = (int*)alloc((size_t)N*4);
  int*   offs   = (int*)alloc((size_t)(N+1)*4);
  int*   cursor = (int*)alloc((size_t)N*4);
  int*   csr    = (int*)alloc((size_t)E*4);
  int*   gstart = (int*)alloc((size_t)B*4);
  int*   gend   = (int*)alloc((size_t)B*4);
  float* hcbuf  = (float*)alloc((size_t)2*B*128*4);
  float* qbuf   = (float*)alloc((size_t)B*128*4);
  float* rsum   = (float*)alloc((size_t)3*B*128*4);
  float* lsum   = (float*)alloc((size_t)3*B*4);

  int npadints = (Mpad - N)*256;
  int nInit = max(max(N, npadints), 256*256);
  init_kernel<<<(nInit+255)/256, 256, 0, stream>>>(counts, gstart, gend,
      rsum, lsum, (int*)(ysplit1 + (size_t)N*256), (int*)(ysplit2 + (size_t)N*256),
      npadints, W1, WT1, W2, WT2, W3, WT3, N, B);
  int gridEN = (max(E,N)+255)/256;
  build_kernel<<<gridEN, 256, 0, stream>>>(ei, batch, counts, gstart, gend, E, N);
  scan_kernel<<<1, 1024, 0, stream>>>(counts, offs, cursor, N);
  fill_kernel<<<(E+255)/256, 256, 0, stream>>>(ei, cursor, csr, E);

  int gm = Mpad/64;
  // ---- layer 1: x (fp32, inline split) -> h bf16 -> ysplit1
  gemm_bf16<true><<<dim3(2,gm), 256, 0, stream>>>((const void*)x, (const short*)WT1,
                                                  hb16, N, 256, 256);
  sd_kernel<4,64><<<(N+3)/4, 256, 0, stream>>>(hb16, as1, ad1, sbuf, dbuf, N);
  agg_kernel<4,64,true><<<N, 256, 0, stream>>>(hb16, sbuf, dbuf, offs, csr, b1, nullptr, ysplit1, N);
  // ---- layer 2: ysplit1 -> h bf16 -> ysplit2
  gemm_bf16<false><<<dim3(2,gm), 256, 0, stream>>>((const void*)ysplit1, (const short*)WT2,
                                                   hb16, N, 512, 256);
  sd_kernel<4,64><<<(N+3)/4, 256, 0, stream>>>(hb16, as2, ad2, sbuf, dbuf, N);
  agg_kernel<4,64,true><<<N, 256, 0, stream>>>(hb16, sbuf, dbuf, offs, csr, b2, nullptr, ysplit2, N);
  // ---- layer 3: ysplit2 -> h bf16 [N,128] -> ybuf (fp32, feeds set2set)
  gemm_bf16<false><<<dim3(1,gm), 256, 0, stream>>>((const void*)ysplit2, (const short*)WT3,
                                                   hb16, N, 512, 128);
  sd_kernel<1,128><<<(N+3)/4, 256, 0, stream>>>(hb16, as3, ad3, sbuf, dbuf, N);
  agg_kernel<1,128,false><<<N, 256, 0, stream>>>(hb16, sbuf, dbuf, offs, csr, b3, ybuf, nullptr, N);

  // ---- set2set (fused grid-parallel readout) + scorer ----
  int gr = (N+31)/32;
  s2s_step_kernel<0><<<B, 256, 0, stream>>>(rsum, lsum, hcbuf, qbuf,
      Wih, Whh, bih, bhh, gfeat, gW1, gb1, gW2, gb2, mW1, mb1, mW2, mb2, (float*)d_out, B);
  read_kernel<<<gr, 256, 0, stream>>>(ybuf, qbuf, batch, rsum + 0*(size_t)B*128, lsum + 0*B, N);
  s2s_step_kernel<1><<<B, 256, 0, stream>>>(rsum, lsum, hcbuf, qbuf,
      Wih, Whh, bih, bhh, gfeat, gW1, gb1, gW2, gb2, mW1, mb1, mW2, mb2, (float*)d_out, B);
  read_kernel<<<gr, 256, 0, stream>>>(ybuf, qbuf, batch, rsum + 1*(size_t)B*128, lsum + 1*B, N);
  s2s_step_kernel<2><<<B, 256, 0, stream>>>(rsum, lsum, hcbuf, qbuf,
      Wih, Whh, bih, bhh, gfeat, gW1, gb1, gW2, gb2, mW1, mb1, mW2, mb2, (float*)d_out, B);
  read_kernel<<<gr, 256, 0, stream>>>(ybuf, qbuf, batch, rsum + 2*(size_t)B*128, lsum + 2*B, N);
  s2s_step_kernel<3><<<B, 256, 0, stream>>>(rsum, lsum, hcbuf, qbuf,
      Wih, Whh, bih, bhh, gfeat, gW1, gb1, gW2, gb2, mW1, mb1, mW2, mb2, (float*)d_out, B);
}

// Round 11
// 524.107 us; speedup vs baseline: 1.0914x; 1.0051x over previous
//
#include <hip/hip_runtime.h>
#include <hip/hip_bf16.h>
#include <math.h>

#define NEG_SLOPE 0.2f

typedef __attribute__((ext_vector_type(8))) short bf16x8;
typedef __attribute__((ext_vector_type(4))) float f32x4;

__device__ __forceinline__ float sigmoidf(float x){ return 1.f/(1.f+expf(-x)); }
__device__ __forceinline__ float bf2f(unsigned us){ return __uint_as_float(us << 16); }

// pack v into (hi,lo) bf16 pair: hi=bf16(v), lo=bf16(v-hi); hi|lo<<16.
__device__ __forceinline__ unsigned pack_split(float v){
  __hip_bfloat16 hi = __float2bfloat16(v);
  float rem = v - __bfloat162float(hi);
  __hip_bfloat16 lo = __float2bfloat16(rem);
  unsigned short uh = __builtin_bit_cast(unsigned short, hi);
  unsigned short ul = __builtin_bit_cast(unsigned short, lo);
  return (unsigned)uh | ((unsigned)ul << 16);
}
__device__ __forceinline__ unsigned short bf16of(float v){
  __hip_bfloat16 h = __float2bfloat16(v);
  return __builtin_bit_cast(unsigned short, h);
}

// ============== init + CSR prep + weight packing (one launch) ===============
// sdbuf: 360000 floats = s1[80000] d1[80000] s2[80000] d2[80000] s3[20000]
// d3[20000] - zeroed here because the gemm epilogue accumulates s,d via
// atomicAdd.
__global__ void init_kernel(int* counts, int* gstart, int* gend,
                            float* rsum, float* lsum, float* sdbuf,
                            int* pad1, int* pad2, int npadints,
                            const float* __restrict__ W1, unsigned* __restrict__ WT1,
                            const float* __restrict__ W2, unsigned* __restrict__ WT2,
                            const float* __restrict__ W3, unsigned* __restrict__ WT3,
                            int n, int b){
  int i = blockIdx.x*blockDim.x + threadIdx.x;
  if (i < n) counts[i] = 0;
  if (i < b){ gstart[i] = 0; gend[i] = 0; }
  if (i < 3*b*128) rsum[i] = 0.f;
  if (i < 3*b) lsum[i] = 0.f;
  if (i < 18*n) sdbuf[i] = 0.f;     // 18*N = 360000
  if (i < npadints){ pad1[i] = 0; pad2[i] = 0; }
  if (i < 128*256){                 // W1 [128,256] -> WT1 [256][128] uints
    int k = i>>8, c = i&255;
    WT1[(size_t)c*128 + k] = pack_split(W1[i]);
  }
  if (i < 256*256){                 // W2 [256,256] -> WT2 [256][256]
    int k = i>>8, c = i&255;
    WT2[(size_t)c*256 + k] = pack_split(W2[i]);
  }
  if (i < 256*128){                 // W3 [256,128] -> WT3 [128][256]
    int k = i>>7, c = i&127;
    WT3[(size_t)c*256 + k] = pack_split(W3[i]);
  }
}

__global__ void build_kernel(const int* __restrict__ ei, const int* __restrict__ batch,
                             int* counts, int* gstart, int* gend, int E, int n){
  int i = blockIdx.x*blockDim.x + threadIdx.x;
  if (i < E) atomicAdd(&counts[ei[E+i]], 1);
  if (i < n){
    int b = batch[i];
    if (i == 0 || batch[i-1] != b) gstart[b] = i;
    if (i == n-1 || batch[i+1] != b) gend[b] = i+1;
  }
}

__global__ void scan_kernel(const int* __restrict__ counts, int* offs, int* cursor, int n){
  const int T = 1024;
  int tid = threadIdx.x;
  int chunk = (n + T - 1)/T;
  int base = tid*chunk;
  int local = 0;
  for (int i=0;i<chunk;i++){ int idx=base+i; if (idx<n) local += counts[idx]; }
  __shared__ int ss[T];
  ss[tid]=local; __syncthreads();
  for (int off=1; off<T; off<<=1){
    int v = (tid>=off)? ss[tid-off] : 0;
    __syncthreads();
    ss[tid]+=v;
    __syncthreads();
  }
  int run = ss[tid]-local;
  for (int i=0;i<chunk;i++){
    int idx=base+i;
    if (idx<n){ offs[idx]=run; cursor[idx]=run; run += counts[idx]; }
  }
  if (tid==T-1) offs[n]=run;
}

__global__ void fill_kernel(const int* __restrict__ ei, int* cursor, int* csr, int E){
  int i = blockIdx.x*blockDim.x + threadIdx.x;
  if (i<E){
    int dst = ei[E+i];
    int pos = atomicAdd(&cursor[dst],1);
    csr[pos] = ei[i];
  }
}

// ===================== bf16 MFMA GEMM (exact via split-K doubling) ==========
// C[M,N] = A x BT^T, bf16 output via LDS-staged coalesced epilogue.
// FUSED sd: per-row partial dots <h, a_src>/<h, a_dst> computed from the
// exact fp32 acc registers and atomicAdd'ed into s,d (zeroed in init).
// H=4: N=256, col head = bn/64 + (nf>=4); H=1: N=128, single head.
template<bool AF32, int H>
__global__ __launch_bounds__(256) void gemm_bf16(
    const void* __restrict__ Aptr, const short* __restrict__ BT,
    unsigned short* __restrict__ Cb16,
    const float* __restrict__ asrc, const float* __restrict__ adst,
    float* __restrict__ sv, float* __restrict__ dv,
    int M, int Ktot, int N){
  __shared__ short As[64][72];
  __shared__ short Bs[128][72];
  int tid = threadIdx.x;
  int wave = tid>>6, lane = tid&63;
  int quad = lane>>4, l16 = lane&15;
  int bm = blockIdx.y*64, bn = blockIdx.x*128;
  f32x4 acc[8];
  #pragma unroll
  for (int i=0;i<8;i++) acc[i] = (f32x4){0.f,0.f,0.f,0.f};
  int rr = tid>>3;          // 0..31
  int seg = (tid&7)*8;      // shorts
  int4 ra[2], rb[4];
  auto loadAB = [&](int k0){
    if (AF32){
      const float* A = (const float*)Aptr;
      int Kf = Ktot>>1;
      int fo = (k0+seg)>>1;
      #pragma unroll
      for (int p=0;p<2;p++){
        int row = bm + p*32 + rr;
        float4 v = make_float4(0.f,0.f,0.f,0.f);
        if (row < M) v = *(const float4*)(A + (size_t)row*Kf + fo);
        ra[p] = make_int4((int)pack_split(v.x),(int)pack_split(v.y),
                          (int)pack_split(v.z),(int)pack_split(v.w));
      }
    } else {
      const short* A = (const short*)Aptr;
      #pragma unroll
      for (int p=0;p<2;p++)
        ra[p] = *(const int4*)(A + (size_t)(bm + p*32 + rr)*Ktot + k0 + seg);
    }
    #pragma unroll
    for (int p=0;p<4;p++)
      rb[p] = *(const int4*)(BT + (size_t)(bn + p*32 + rr)*Ktot + k0 + seg);
  };
  loadAB(0);
  for (int k0=0; k0<Ktot; k0+=64){
    __syncthreads();
    #pragma unroll
    for (int p=0;p<2;p++) *(int4*)&As[p*32+rr][seg] = ra[p];
    #pragma unroll
    for (int p=0;p<4;p++) *(int4*)&Bs[p*32+rr][seg] = rb[p];
    __syncthreads();
    if (k0+64 < Ktot) loadAB(k0+64);   // prefetch; regs free (already stored)
    #pragma unroll
    for (int kk=0;kk<2;kk++){
      bf16x8 af = *(bf16x8*)&As[wave*16 + l16][kk*32 + quad*8];
      #pragma unroll
      for (int nf=0;nf<8;nf++){
        bf16x8 bfv = *(bf16x8*)&Bs[nf*16 + l16][kk*32 + quad*8];
        acc[nf] = __builtin_amdgcn_mfma_f32_16x16x32_bf16(af, bfv, acc[nf], 0,0,0);
      }
    }
  }
  // ---- fused sd: partial <h,a> dots from exact fp32 acc ----
  float av[8], bv[8];
  #pragma unroll
  for (int nf=0;nf<8;nf++){
    int c = bn + nf*16 + l16;
    av[nf] = asrc[c];
    bv[nf] = adst[c];
  }
  #pragma unroll
  for (int r=0;r<4;r++){
    int row = bm + wave*16 + quad*4 + r;
    float psA=0.f, pdA=0.f, psB=0.f, pdB=0.f;
    #pragma unroll
    for (int nf=0;nf<4;nf++){ psA += acc[nf][r]*av[nf]; pdA += acc[nf][r]*bv[nf]; }
    #pragma unroll
    for (int nf=4;nf<8;nf++){ psB += acc[nf][r]*av[nf]; pdB += acc[nf][r]*bv[nf]; }
    #pragma unroll
    for (int off=1; off<16; off<<=1){
      psA += __shfl_xor(psA,off); pdA += __shfl_xor(pdA,off);
      psB += __shfl_xor(psB,off); pdB += __shfl_xor(pdB,off);
    }
    if (l16==0 && row < M){
      if (H == 4){
        int h0 = bn>>6;     // 2 heads per 128-col block
        atomicAdd(&sv[row*4 + h0],     psA);
        atomicAdd(&dv[row*4 + h0],     pdA);
        atomicAdd(&sv[row*4 + h0 + 1], psB);
        atomicAdd(&dv[row*4 + h0 + 1], pdB);
      } else {
        atomicAdd(&sv[row], psA + psB);
        atomicAdd(&dv[row], pdA + pdB);
      }
    }
  }
  // ---- coalesced bf16 epilogue via LDS staging ----
  // C/D layout: col=lane&15, row=quad*4+reg (m89/m91 verified)
  __syncthreads();                       // all frag reads done; reuse As
  unsigned short* stg = (unsigned short*)(&As[0][0]) + wave*528;  // 4x132 shorts
  #pragma unroll
  for (int r=0;r<4;r++){
    #pragma unroll
    for (int nf=0;nf<8;nf++)
      stg[quad*132 + nf*16 + l16] = bf16of(acc[nf][r]);
    #pragma unroll
    for (int p=0;p<4;p++){
      int row = bm + wave*16 + p*4 + r;
      if (row < M){
        unsigned v = (unsigned)stg[p*132 + lane*2] |
                     ((unsigned)stg[p*132 + lane*2 + 1] << 16);
        *(unsigned*)(Cb16 + (size_t)row*N + bn + lane*2) = v;
      }
    }
  }
}

// ================= GAT aggregation: softmax over in-edges ====================
template<int H, int C, bool SPLIT>
__global__ __launch_bounds__(256) void agg_kernel(
    const unsigned short* __restrict__ hb, const float* __restrict__ s,
    const float* __restrict__ d, const int* __restrict__ offs,
    const int* __restrict__ csr, const float* __restrict__ bias,
    float* __restrict__ yf, unsigned* __restrict__ ys, int n_nodes){
  constexpr int HC = H*C;
  constexpr int VEC = HC/64;            // 4 (H=4,C=64) or 2 (H=1,C=128)
  int n = blockIdx.x;
  int tid = threadIdx.x;
  int wave = tid>>6, lane = tid&63;
  __shared__ float sdst[H];
  __shared__ float sl[H];
  __shared__ float sw[64*H];
  __shared__ int ssrc[64];
  __shared__ float facc[4][HC];
  if (tid < H) sdst[tid] = d[n*H+tid];
  int start = offs[n];
  int cnt = offs[n+1]-start;
  int cnt1 = cnt+1;                      // + self loop
  __syncthreads();
  float acc[VEC] = {};
  float lp[H];
  #pragma unroll
  for (int h=0;h<H;h++) lp[h]=0.f;
  for (int base=0; base<cnt1; base+=64){
    int nchunk = min(64, cnt1-base);
    if (tid < nchunk){
      int i = base+tid;
      int src = (i==cnt) ? n : csr[start+i];
      ssrc[tid]=src;
      if (H == 4){
        float4 sv = *reinterpret_cast<const float4*>(s + (size_t)src*4);
        float ev[4] = {sv.x, sv.y, sv.z, sv.w};
        #pragma unroll
        for (int h=0;h<4;h++){
          float e = ev[h] + sdst[h];
          e = e>=0.f ? e : NEG_SLOPE*e;
          float w = expf(e);
          sw[tid*4+h]=w;
          lp[h]+=w;
        }
      } else {
        float e = s[src] + sdst[0];
        e = e>=0.f ? e : NEG_SLOPE*e;
        float w = expf(e);
        sw[tid]=w;
        lp[0]+=w;
      }
    }
    __syncthreads();
    for (int j=wave; j<nchunk; j+=4){
      int src = ssrc[j];
      const unsigned short* hp = hb + (size_t)src*HC + lane*VEC;
      if (VEC == 4){
        float wt = sw[j*H + (lane>>4)];
        int2 hv = *reinterpret_cast<const int2*>(hp);
        acc[0] += wt*bf2f((unsigned)hv.x & 0xFFFFu);
        acc[1] += wt*bf2f((unsigned)hv.x >> 16);
        acc[2] += wt*bf2f((unsigned)hv.y & 0xFFFFu);
        acc[3] += wt*bf2f((unsigned)hv.y >> 16);
      } else {
        float wt = sw[j];
        unsigned hv = *reinterpret_cast<const unsigned*>(hp);
        acc[0] += wt*bf2f(hv & 0xFFFFu);
        acc[1] += wt*bf2f(hv >> 16);
      }
    }
    __syncthreads();
  }
  if (wave==0){
    #pragma unroll
    for (int off=32; off; off>>=1)
      #pragma unroll
      for (int h=0;h<H;h++) lp[h] += __shfl_down(lp[h],off);
    if (lane==0)
      #pragma unroll
      for (int h=0;h<H;h++) sl[h]=lp[h];
  }
  #pragma unroll
  for (int v=0;v<VEC;v++) facc[wave][lane*VEC+v] = acc[v];
  __syncthreads();
  if (tid < HC){
    float a = facc[0][tid]+facc[1][tid]+facc[2][tid]+facc[3][tid];
    int head = tid / C;
    float o = a/(sl[head]+1e-16f) + bias[tid];
    o = o>0.f ? o : expm1f(o);
    if (SPLIT){
      ys[(size_t)n*HC + tid] = pack_split(o);
    } else {
      yf[(size_t)n*HC + tid] = o;
    }
  }
}

// ======================= Set2Set, grid-parallel =============================
__global__ __launch_bounds__(256) void read_kernel(
    const float* __restrict__ x, const float* __restrict__ q,
    const int* __restrict__ batch,
    float* __restrict__ rsum, float* __restrict__ lsum, int N){
  int tid = threadIdx.x;
  int wave = tid>>6, lane = tid&63;
  int c0 = blockIdx.x*32;
  if (c0 >= N) return;
  __shared__ float ws[32];
  __shared__ int gb[32];
  if (tid < 32 && c0+tid < N) gb[tid] = batch[c0+tid];
  __syncthreads();
  #pragma unroll
  for (int j=0;j<8;j++){
    int k = wave*8 + j;
    int i = c0 + k;
    if (i < N){
      int g = gb[k];
      float2 xv = *reinterpret_cast<const float2*>(x + (size_t)i*128 + lane*2);
      float2 qv = *reinterpret_cast<const float2*>(q + (size_t)g*128 + lane*2);
      float p = xv.x*qv.x + xv.y*qv.y;
      #pragma unroll
      for (int off=32; off; off>>=1) p += __shfl_down(p, off);
      if (lane==0) ws[k] = expf(p);
    }
  }
  __syncthreads();
  if (tid < 128){
    int col = tid;
    int endi = min(c0+32, N);
    int curg = gb[0];
    float acc = 0.f, lacc = 0.f;
    for (int i=c0; i<endi; ++i){
      int g = gb[i-c0];
      if (g != curg){
        atomicAdd(&rsum[curg*128+col], acc);
        if (col==0) atomicAdd(&lsum[curg], lacc);
        acc = 0.f; lacc = 0.f; curg = g;
      }
      float w = ws[i-c0];
      acc += w * x[(size_t)i*128+col];
      lacc += w;
    }
    atomicAdd(&rsum[curg*128+col], acc);
    if (col==0) atomicAdd(&lsum[curg], lacc);
  }
}

template<int STEP>
__global__ __launch_bounds__(256) void s2s_step_kernel(
    const float* __restrict__ rsum, const float* __restrict__ lsum,
    float* __restrict__ hc, float* __restrict__ qbuf,
    const float* __restrict__ Wih, const float* __restrict__ Whh,
    const float* __restrict__ bih, const float* __restrict__ bhh,
    const float* __restrict__ gfeat,
    const float* __restrict__ gW1, const float* __restrict__ gb1,
    const float* __restrict__ gW2, const float* __restrict__ gb2,
    const float* __restrict__ mW1, const float* __restrict__ mb1,
    const float* __restrict__ mW2, const float* __restrict__ mb2,
    float* __restrict__ out, int B){
  int b = blockIdx.x, tid = threadIdx.x;
  __shared__ float qs[256];

  if (STEP > 0){
    if (tid < 128){
      const float* rs = rsum + (size_t)(STEP-1)*B*128 + (size_t)b*128;
      float ls = lsum[(STEP-1)*B + b];
      qs[tid]     = qbuf[b*128+tid];
      qs[128+tid] = rs[tid] / (ls + 1e-16f);
    }
    __syncthreads();
  }

  if (STEP < 3){
    __shared__ float hs[128], gsh[512];
    if (STEP > 0){ if (tid<128) hs[tid] = hc[(size_t)b*128+tid]; }
    __syncthreads();
    #pragma unroll
    for (int p=0;p<2;p++){
      int j = tid + p*256;
      float a = bih[j] + bhh[j];
      if (STEP > 0){
        const float* wi = Wih + (size_t)j*256;
        for (int k=0;k<256;k+=4)
          a += qs[k]*wi[k] + qs[k+1]*wi[k+1] + qs[k+2]*wi[k+2] + qs[k+3]*wi[k+3];
        const float* wh = Whh + (size_t)j*128;
        for (int k=0;k<128;k+=4)
          a += hs[k]*wh[k] + hs[k+1]*wh[k+1] + hs[k+2]*wh[k+2] + hs[k+3]*wh[k+3];
      }
      gsh[j] = a;
    }
    __syncthreads();
    if (tid < 128){
      float cprev = (STEP==0) ? 0.f : hc[(size_t)(B+b)*128+tid];
      float ig = sigmoidf(gsh[tid]);
      float fg = sigmoidf(gsh[128+tid]);
      float gg = tanhf(gsh[256+tid]);
      float og = sigmoidf(gsh[384+tid]);
      float c2 = fg*cprev + ig*gg;
      float h2 = og*tanhf(c2);
      hc[(size_t)b*128+tid] = h2;
      hc[(size_t)(B+b)*128+tid] = c2;
      qbuf[b*128+tid] = h2;
    }
  } else {
    __shared__ float z[288], gf1[64], hid[128];
    z[tid] = qs[tid];
    if (tid < 64){
      float a = gb1[tid];
      for (int k=0;k<9;k++) a += gfeat[b*9+k]*gW1[k*64+tid];
      gf1[tid] = a>0.f ? a : 0.f;
    }
    __syncthreads();
    if (tid < 32){
      float a = gb2[tid];
      for (int k=0;k<64;k++) a += gf1[k]*gW2[k*32+tid];
      z[256+tid] = a;
    }
    __syncthreads();
    if (tid < 128){
      float a = mb1[tid];
      for (int k=0;k<288;k++) a += z[k]*mW1[(size_t)k*128+tid];
      hid[tid] = a>0.f ? a : 0.f;
    }
    __syncthreads();
    if (tid < 4){
      float a = mb2[tid];
      for (int k=0;k<128;k++) a += hid[k]*mW2[k*4+tid];
      out[b*4+tid] = a;
    }
  }
}

// ================================ launch ====================================
extern "C" void kernel_launch(void* const* d_in, const int* in_sizes, int n_in,
                              void* d_out, int out_size, void* d_ws, size_t ws_size,
                              hipStream_t stream) {
  const float* x     = (const float*)d_in[0];
  const int*   ei    = (const int*)d_in[1];
  const int*   batch = (const int*)d_in[2];
  const float* gfeat = (const float*)d_in[3];
  const float* W1    = (const float*)d_in[4];
  const float* as1   = (const float*)d_in[5];
  const float* ad1   = (const float*)d_in[6];
  const float* b1    = (const float*)d_in[7];
  const float* W2    = (const float*)d_in[8];
  const float* as2   = (const float*)d_in[9];
  const float* ad2   = (const float*)d_in[10];
  const float* b2    = (const float*)d_in[11];
  const float* W3    = (const float*)d_in[12];
  const float* as3   = (const float*)d_in[13];
  const float* ad3   = (const float*)d_in[14];
  const float* b3    = (const float*)d_in[15];
  const float* Wih   = (const float*)d_in[16];
  const float* Whh   = (const float*)d_in[17];
  const float* bih   = (const float*)d_in[18];
  const float* bhh   = (const float*)d_in[19];
  const float* gW1   = (const float*)d_in[20];
  const float* gb1   = (const float*)d_in[21];
  const float* gW2   = (const float*)d_in[22];
  const float* gb2   = (const float*)d_in[23];
  const float* mW1   = (const float*)d_in[24];
  const float* mb1   = (const float*)d_in[25];
  const float* mW2   = (const float*)d_in[26];
  const float* mb2   = (const float*)d_in[27];

  const int N = in_sizes[0]/128;   // 20000
  const int E = in_sizes[1]/2;     // 320000
  const int B = in_sizes[3]/9;     // 64
  const int Mpad = ((N + 127)/128)*128;   // 20096

  char* ws = (char*)d_ws;
  size_t off = 0;
  auto alloc = [&](size_t bytes)->char*{
    char* p = ws + off;
    off += (bytes + 255) & ~(size_t)255;
    return p;
  };
  unsigned short* hb16 = (unsigned short*)alloc((size_t)N*256*2);   // bf16 h
  unsigned* ysplit1 = (unsigned*)alloc((size_t)Mpad*256*4);
  unsigned* ysplit2 = (unsigned*)alloc((size_t)Mpad*256*4);
  float*    ybuf    = (float*)alloc((size_t)N*128*4);
  unsigned* WT1     = (unsigned*)alloc((size_t)256*128*4);
  unsigned* WT2     = (unsigned*)alloc((size_t)256*256*4);
  unsigned* WT3     = (unsigned*)alloc((size_t)128*256*4);
  float* sdbuf  = (float*)alloc((size_t)18*N*4);   // s1 d1 s2 d2 s3 d3
  int*   counts = (int*)alloc((size_t)N*4);
  int*   offs   = (int*)alloc((size_t)(N+1)*4);
  int*   cursor = (int*)alloc((size_t)N*4);
  int*   csr    = (int*)alloc((size_t)E*4);
  int*   gstart = (int*)alloc((size_t)B*4);
  int*   gend   = (int*)alloc((size_t)B*4);
  float* hcbuf  = (float*)alloc((size_t)2*B*128*4);
  float* qbuf   = (float*)alloc((size_t)B*128*4);
  float* rsum   = (float*)alloc((size_t)3*B*128*4);
  float* lsum   = (float*)alloc((size_t)3*B*4);

  float* s1 = sdbuf;            float* d1 = sdbuf + (size_t)4*N;
  float* s2 = sdbuf + (size_t)8*N;  float* d2 = sdbuf + (size_t)12*N;
  float* s3 = sdbuf + (size_t)16*N; float* d3 = sdbuf + (size_t)17*N;

  int npadints = (Mpad - N)*256;
  int nInit = 18*N;   // covers sdbuf (largest), counts, rsum, W packs, pads
  if (npadints > nInit) nInit = npadints;
  if (256*256 > nInit) nInit = 256*256;
  init_kernel<<<(nInit+255)/256, 256, 0, stream>>>(counts, gstart, gend,
      rsum, lsum, sdbuf,
      (int*)(ysplit1 + (size_t)N*256), (int*)(ysplit2 + (size_t)N*256),
      npadints, W1, WT1, W2, WT2, W3, WT3, N, B);
  int gridEN = (max(E,N)+255)/256;
  build_kernel<<<gridEN, 256, 0, stream>>>(ei, batch, counts, gstart, gend, E, N);
  scan_kernel<<<1, 1024, 0, stream>>>(counts, offs, cursor, N);
  fill_kernel<<<(E+255)/256, 256, 0, stream>>>(ei, cursor, csr, E);

  int gm = Mpad/64;
  // ---- layer 1: x (fp32, inline split) -> h bf16 + s1,d1 -> ysplit1
  gemm_bf16<true,4><<<dim3(2,gm), 256, 0, stream>>>((const void*)x, (const short*)WT1,
      hb16, as1, ad1, s1, d1, N, 256, 256);
  agg_kernel<4,64,true><<<N, 256, 0, stream>>>(hb16, s1, d1, offs, csr, b1, nullptr, ysplit1, N);
  // ---- layer 2: ysplit1 -> h bf16 + s2,d2 -> ysplit2
  gemm_bf16<false,4><<<dim3(2,gm), 256, 0, stream>>>((const void*)ysplit1, (const short*)WT2,
      hb16, as2, ad2, s2, d2, N, 512, 256);
  agg_kernel<4,64,true><<<N, 256, 0, stream>>>(hb16, s2, d2, offs, csr, b2, nullptr, ysplit2, N);
  // ---- layer 3: ysplit2 -> h bf16 [N,128] + s3,d3 -> ybuf (fp32)
  gemm_bf16<false,1><<<dim3(1,gm), 256, 0, stream>>>((const void*)ysplit2, (const short*)WT3,
      hb16, as3, ad3, s3, d3, N, 512, 128);
  agg_kernel<1,128,false><<<N, 256, 0, stream>>>(hb16, s3, d3, offs, csr, b3, ybuf, nullptr, N);

  // ---- set2set (fused grid-parallel readout) + scorer ----
  int gr = (N+31)/32;
  s2s_step_kernel<0><<<B, 256, 0, stream>>>(rsum, lsum, hcbuf, qbuf,
      Wih, Whh, bih, bhh, gfeat, gW1, gb1, gW2, gb2, mW1, mb1, mW2, mb2, (float*)d_out, B);
  read_kernel<<<gr, 256, 0, stream>>>(ybuf, qbuf, batch, rsum + 0*(size_t)B*128, lsum + 0*B, N);
  s2s_step_kernel<1><<<B, 256, 0, stream>>>(rsum, lsum, hcbuf, qbuf,
      Wih, Whh, bih, bhh, gfeat, gW1, gb1, gW2, gb2, mW1, mb1, mW2, mb2, (float*)d_out, B);
  read_kernel<<<gr, 256, 0, stream>>>(ybuf, qbuf, batch, rsum + 1*(size_t)B*128, lsum + 1*B, N);
  s2s_step_kernel<2><<<B, 256, 0, stream>>>(rsum, lsum, hcbuf, qbuf,
      Wih, Whh, bih, bhh, gfeat, gW1, gb1, gW2, gb2, mW1, mb1, mW2, mb2, (float*)d_out, B);
  read_kernel<<<gr, 256, 0, stream>>>(ybuf, qbuf, batch, rsum + 2*(size_t)B*128, lsum + 2*B, N);
  s2s_step_kernel<3><<<B, 256, 0, stream>>>(rsum, lsum, hcbuf, qbuf,
      Wih, Whh, bih, bhh, gfeat, gW1, gb1, gW2, gb2, mW1, mb1, mW2, mb2, (float*)d_out, B);
}